// Round 2
// baseline (366.163 us; speedup 1.0000x reference)
//
#include <hip/hip_runtime.h>
#include <hip/hip_bf16.h>
#include <cmath>

// I/O: all inputs float32 (per reference setup_inputs), output float32.
// Internal compute: bf16 MFMA with fp32 accumulation.
//
// Workspace layout (64 MB total):
//  [0,16M)   WqkvT  [4096][2048] bf16   (rows: 0-2047 WqT, 2048-3071 WkT, 3072-4095 WvT)
//  [16,24M)  WoT    [2048][2048] bf16
//  [24,40M)  QKVraw [2048][4096] bf16
//  [40,48M)  Qn     [2048][2048] bf16   (post rms+rope)
//  [48,52M)  Kn     [2048][1024] bf16
//  [52,56M)  Vt     [1024][2048] bf16   ([hkv*128 d][s])
//  [56,64M)  hsb    [2048][2048] bf16   (live: kernels 1-2)   }  overlaid,
//  [56,64M)  AT     [2048][2048] bf16   (live: kernels 6-7)   }  disjoint liveness

typedef __bf16 bf16x8 __attribute__((ext_vector_type(8)));
typedef float  f32x4  __attribute__((ext_vector_type(4)));

#define S_LEN    2048
#define NH       16
#define NKV      8
#define HDIM     128
#define WIN      1024
#define QK_SCALE 0.08838834764831845f
#define RMS_EPS  1e-6f

__device__ __forceinline__ void gld16(void* lds, const void* g) {
    __builtin_amdgcn_global_load_lds(
        (const __attribute__((address_space(1))) unsigned int*)g,
        (__attribute__((address_space(3))) unsigned int*)lds, 16, 0, 0);
}

__device__ __forceinline__ unsigned short f2bu(float x) {
    __hip_bfloat16 h = __float2bfloat16(x);
    return *(unsigned short*)&h;
}

// ---------------------------------------------------------------------------
// hidden_states f32 -> bf16, 8 elems/thread
// ---------------------------------------------------------------------------
__global__ __launch_bounds__(256) void cvt_hs_kernel(
    const float* __restrict__ src, __hip_bfloat16* __restrict__ dst)
{
    size_t i = ((size_t)blockIdx.x * 256 + threadIdx.x) * 8;
    float4 a = *(const float4*)(src + i);
    float4 b = *(const float4*)(src + i + 4);
    unsigned short u[8] = { f2bu(a.x), f2bu(a.y), f2bu(a.z), f2bu(a.w),
                            f2bu(b.x), f2bu(b.y), f2bu(b.z), f2bu(b.w) };
    *(uint4*)(dst + i) = *(uint4*)u;
}

// ---------------------------------------------------------------------------
// Weight transpose + f32->bf16: W[K][N] f32 -> WT[N][K] bf16, 64x64 tiles.
// ---------------------------------------------------------------------------
__global__ __launch_bounds__(256) void transpose_w_kernel(
    const float* __restrict__ Wq, const float* __restrict__ Wk,
    const float* __restrict__ Wv, const float* __restrict__ Wo,
    __hip_bfloat16* __restrict__ WqkvT, __hip_bfloat16* __restrict__ WoT)
{
    __shared__ __attribute__((aligned(16))) unsigned short tile[64][72]; // 144B rows, 16B-aligned
    int id = blockIdx.x;
    const float* src; __hip_bfloat16* dst; int N, kt, nt;
    if (id < 1024)      { src = Wq; dst = WqkvT;                          N = 2048; kt = id >> 5;          nt = id & 31; }
    else if (id < 1536) { src = Wk; dst = WqkvT + (size_t)2048*2048;      N = 1024; kt = (id-1024) >> 4;   nt = (id-1024) & 15; }
    else if (id < 2048) { src = Wv; dst = WqkvT + (size_t)3072*2048;      N = 1024; kt = (id-1536) >> 4;   nt = (id-1536) & 15; }
    else                { src = Wo; dst = WoT;                            N = 2048; kt = (id-2048) >> 5;   nt = (id-2048) & 31; }
    int k0 = kt * 64, n0 = nt * 64;
    int tid = threadIdx.x;
#pragma unroll
    for (int p = 0; p < 2; ++p) {
        int c = p*256 + tid; int r = c >> 3, cc = (c & 7) * 8;
        const float* s = src + (size_t)(k0 + r)*N + n0 + cc;
        float4 a = *(const float4*)s;
        float4 b = *(const float4*)(s + 4);
        unsigned short u[8] = { f2bu(a.x), f2bu(a.y), f2bu(a.z), f2bu(a.w),
                                f2bu(b.x), f2bu(b.y), f2bu(b.z), f2bu(b.w) };
        *(uint4*)&tile[r][cc] = *(uint4*)u;
    }
    __syncthreads();
#pragma unroll
    for (int p = 0; p < 2; ++p) {
        int c = p*256 + tid; int r2 = c >> 3, c2 = (c & 7) * 8;
        uint4 o;
        o.x = tile[c2+0][r2] | ((unsigned)tile[c2+1][r2] << 16);
        o.y = tile[c2+2][r2] | ((unsigned)tile[c2+3][r2] << 16);
        o.z = tile[c2+4][r2] | ((unsigned)tile[c2+5][r2] << 16);
        o.w = tile[c2+6][r2] | ((unsigned)tile[c2+7][r2] << 16);
        *(uint4*)(dst + (size_t)(n0 + r2)*2048 + k0 + c2) = o;
    }
}

// ---------------------------------------------------------------------------
// V transpose: QKVraw[s][3072 + v] bf16 -> Vt[v][s] bf16
// ---------------------------------------------------------------------------
__global__ __launch_bounds__(256) void vtrans_kernel(
    const __hip_bfloat16* __restrict__ qkv, __hip_bfloat16* __restrict__ Vt)
{
    __shared__ __attribute__((aligned(16))) unsigned short tile[64][72];
    int s0 = blockIdx.x * 64;
    int v0 = blockIdx.y * 64;
    int tid = threadIdx.x;
#pragma unroll
    for (int p = 0; p < 2; ++p) {
        int c = p*256 + tid; int r = c >> 3, cc = (c & 7) * 8;
        uint4 v = *(const uint4*)(qkv + (size_t)(s0 + r)*4096 + 3072 + v0 + cc);
        *(uint4*)&tile[r][cc] = v;
    }
    __syncthreads();
#pragma unroll
    for (int p = 0; p < 2; ++p) {
        int c = p*256 + tid; int r2 = c >> 3, c2 = (c & 7) * 8;
        uint4 o;
        o.x = tile[c2+0][r2] | ((unsigned)tile[c2+1][r2] << 16);
        o.y = tile[c2+2][r2] | ((unsigned)tile[c2+3][r2] << 16);
        o.z = tile[c2+4][r2] | ((unsigned)tile[c2+5][r2] << 16);
        o.w = tile[c2+6][r2] | ((unsigned)tile[c2+7][r2] << 16);
        *(uint4*)(Vt + (size_t)(v0 + r2)*2048 + s0 + c2) = o;
    }
}

// ---------------------------------------------------------------------------
// GEMM: C[M][N] = A[M][K] * BT[N][K]^T.  128x128 tile, BK=32, 4 waves (2x2),
// global_load_lds staging, mfma_f32_16x16x32_bf16 (m97 structure).
// OT = __hip_bfloat16 (internal) or float (final output).
// ---------------------------------------------------------------------------
template <typename OT>
__global__ __launch_bounds__(256) void gemm_bt_kernel(
    const __hip_bfloat16* __restrict__ A, const __hip_bfloat16* __restrict__ BT,
    OT* __restrict__ C, int M, int N, int K)
{
    __shared__ __attribute__((aligned(16))) __hip_bfloat16 As[128*32];
    __shared__ __attribute__((aligned(16))) __hip_bfloat16 Bs[128*32];
    const int tid  = threadIdx.x;
    const int lane = tid & 63;
    const int wave = tid >> 6;
    const int quad = lane >> 4, l15 = lane & 15;
    const int m0 = blockIdx.y * 128, n0 = blockIdx.x * 128;
    const int wm = (wave >> 1) * 64, wn = (wave & 1) * 64;

    f32x4 acc[4][4] = {};

    for (int k0 = 0; k0 < K; k0 += 32) {
#pragma unroll
        for (int p = 0; p < 2; ++p) {
            int c = p*256 + tid;
            int row = c >> 2, seg = c & 3;
            gld16((char*)As + c*16, A  + (size_t)(m0 + row)*K + k0 + seg*8);
            gld16((char*)Bs + c*16, BT + (size_t)(n0 + row)*K + k0 + seg*8);
        }
        __syncthreads();
        bf16x8 af[4], bfr[4];
#pragma unroll
        for (int t = 0; t < 4; ++t) {
            af[t]  = *(const bf16x8*)(As + (wm + t*16 + l15)*32 + quad*8);
            bfr[t] = *(const bf16x8*)(Bs + (wn + t*16 + l15)*32 + quad*8);
        }
#pragma unroll
        for (int mt = 0; mt < 4; ++mt)
#pragma unroll
            for (int nt = 0; nt < 4; ++nt)
                acc[mt][nt] = __builtin_amdgcn_mfma_f32_16x16x32_bf16(af[mt], bfr[nt], acc[mt][nt], 0, 0, 0);
        __syncthreads();
    }
#pragma unroll
    for (int mt = 0; mt < 4; ++mt)
#pragma unroll
        for (int nt = 0; nt < 4; ++nt)
#pragma unroll
            for (int r = 0; r < 4; ++r) {
                int row = m0 + wm + mt*16 + quad*4 + r;
                int col = n0 + wn + nt*16 + l15;
                if constexpr (__is_same(OT, float))
                    C[(size_t)row*N + col] = acc[mt][nt][r];
                else
                    C[(size_t)row*N + col] = __float2bfloat16(acc[mt][nt][r]);
            }
}

// ---------------------------------------------------------------------------
// RMSNorm + RoPE on Q and K rows of QKVraw. Block per s; wave per head-unit.
// cos/sin/scales are f32.
// ---------------------------------------------------------------------------
__global__ __launch_bounds__(256) void rmsrope_kernel(
    const __hip_bfloat16* __restrict__ qkv,
    const float* __restrict__ cosb, const float* __restrict__ sinb,
    const float* __restrict__ qsc,  const float* __restrict__ ksc,
    __hip_bfloat16* __restrict__ Qn, __hip_bfloat16* __restrict__ Kn)
{
    int s = blockIdx.x;
    int wave = threadIdx.x >> 6, lane = threadIdx.x & 63;
    float c1 = cosb[s*128 + lane];
    float c2 = cosb[s*128 + 64 + lane];
    float s1 = sinb[s*128 + lane];
    float s2 = sinb[s*128 + 64 + lane];
    for (int u = wave; u < 24; u += 4) {
        bool isq = (u < 16);
        int h = isq ? u : u - 16;
        const __hip_bfloat16* x = qkv + (size_t)s*4096 + (isq ? h*128 : 2048 + h*128);
        float x1 = (float)x[lane], x2 = (float)x[lane + 64];
        float ss = x1*x1 + x2*x2;
#pragma unroll
        for (int off = 32; off; off >>= 1) ss += __shfl_xor(ss, off);
        float r = rsqrtf(ss * (1.0f/128.0f) + RMS_EPS);
        const float* sc = isq ? qsc : ksc;
        float y1 = x1 * r * sc[lane];
        float y2 = x2 * r * sc[lane + 64];
        float o1 = y1*c1 - y2*s1;   // d < 64:  x*c - x[d+64]*s
        float o2 = y2*c2 + y1*s2;   // d >= 64: x*c + x[d-64]*s
        __hip_bfloat16* dst = isq ? (Qn + (size_t)s*2048 + h*128)
                                  : (Kn + (size_t)s*1024 + h*128);
        dst[lane]      = __float2bfloat16(o1);
        dst[lane + 64] = __float2bfloat16(o2);
    }
}

// ---------------------------------------------------------------------------
// Flash attention, sliding-window causal. Block = (head h, 64 q rows).
// 4 waves x 16 q-rows. K-tiles of 64 keys. GQA: kv head = h >> 1.
// ---------------------------------------------------------------------------
__global__ __launch_bounds__(256) void attn_kernel(
    const __hip_bfloat16* __restrict__ Qn,  // [S][2048]
    const __hip_bfloat16* __restrict__ Kn,  // [S][1024]
    const __hip_bfloat16* __restrict__ Vt,  // [1024][S]
    __hip_bfloat16* __restrict__ O)         // [S][2048]
{
    __shared__ __attribute__((aligned(16))) __hip_bfloat16 P[4][16][72];
    const int h  = blockIdx.x;
    const int i0 = blockIdx.y * 64;
    const int hk = h >> 1;
    const int tid = threadIdx.x, wave = tid >> 6, lane = tid & 63;
    const int quad = lane >> 4, l15 = lane & 15;
    const int ib = i0 + wave * 16;

    bf16x8 qf[4];
    const __hip_bfloat16* qbase = Qn + (size_t)(ib + l15)*2048 + h*HDIM + quad*8;
#pragma unroll
    for (int kk = 0; kk < 4; ++kk) qf[kk] = *(const bf16x8*)(qbase + kk*32);

    f32x4 o[8] = {};
    float mrow[4], lrow[4];
#pragma unroll
    for (int r = 0; r < 4; ++r) { mrow[r] = -INFINITY; lrow[r] = 0.f; }

    int jstart = i0 - WIN; if (jstart < 0) jstart = 0;
    for (int j0 = jstart; j0 <= i0; j0 += 64) {
        // ---- S = Q K^T (16 x 64 per wave) ----
        f32x4 sacc[4] = {};
#pragma unroll
        for (int nt = 0; nt < 4; ++nt) {
            const __hip_bfloat16* kb = Kn + (size_t)(j0 + nt*16 + l15)*1024 + hk*HDIM + quad*8;
#pragma unroll
            for (int kk = 0; kk < 4; ++kk) {
                bf16x8 kf = *(const bf16x8*)(kb + kk*32);
                sacc[nt] = __builtin_amdgcn_mfma_f32_16x16x32_bf16(qf[kk], kf, sacc[nt], 0, 0, 0);
            }
        }
        // ---- mask, online softmax ----
        float sval[4][4];
        float tmax[4] = {-INFINITY, -INFINITY, -INFINITY, -INFINITY};
#pragma unroll
        for (int nt = 0; nt < 4; ++nt) {
            int j = j0 + nt*16 + l15;
#pragma unroll
            for (int r = 0; r < 4; ++r) {
                int i = ib + quad*4 + r;
                bool valid = (j <= i) && (i - j <= WIN);
                float sv = valid ? sacc[nt][r] * QK_SCALE : -INFINITY;
                sval[nt][r] = sv;
                tmax[r] = fmaxf(tmax[r], sv);
            }
        }
#pragma unroll
        for (int r = 0; r < 4; ++r) {
            tmax[r] = fmaxf(tmax[r], __shfl_xor(tmax[r], 1));
            tmax[r] = fmaxf(tmax[r], __shfl_xor(tmax[r], 2));
            tmax[r] = fmaxf(tmax[r], __shfl_xor(tmax[r], 4));
            tmax[r] = fmaxf(tmax[r], __shfl_xor(tmax[r], 8));
        }
        float alpha[4], rsum[4];
#pragma unroll
        for (int r = 0; r < 4; ++r) {
            float mnew = fmaxf(mrow[r], tmax[r]);
            alpha[r] = (mrow[r] == -INFINITY) ? 0.f : __expf(mrow[r] - mnew);
            mrow[r] = mnew;
            rsum[r] = 0.f;
        }
#pragma unroll
        for (int nt = 0; nt < 4; ++nt)
#pragma unroll
            for (int r = 0; r < 4; ++r) {
                float p = (sval[nt][r] == -INFINITY) ? 0.f : __expf(sval[nt][r] - mrow[r]);
                rsum[r] += p;
                P[wave][quad*4 + r][nt*16 + l15] = __float2bfloat16(p);
            }
#pragma unroll
        for (int r = 0; r < 4; ++r) {
            rsum[r] += __shfl_xor(rsum[r], 1);
            rsum[r] += __shfl_xor(rsum[r], 2);
            rsum[r] += __shfl_xor(rsum[r], 4);
            rsum[r] += __shfl_xor(rsum[r], 8);
            lrow[r] = lrow[r]*alpha[r] + rsum[r];
#pragma unroll
            for (int dt = 0; dt < 8; ++dt) o[dt][r] *= alpha[r];
        }
        __syncthreads();
        // ---- O += P V ----
#pragma unroll
        for (int ks = 0; ks < 2; ++ks) {
            bf16x8 pf = *(const bf16x8*)&P[wave][l15][ks*32 + quad*8];
#pragma unroll
            for (int dt = 0; dt < 8; ++dt) {
                const __hip_bfloat16* vb = Vt + (size_t)(hk*HDIM + dt*16 + l15)*2048 + j0 + ks*32 + quad*8;
                bf16x8 vf = *(const bf16x8*)vb;
                o[dt] = __builtin_amdgcn_mfma_f32_16x16x32_bf16(pf, vf, o[dt], 0, 0, 0);
            }
        }
    }
    // ---- epilogue ----
#pragma unroll
    for (int r = 0; r < 4; ++r) {
        float inv = 1.0f / lrow[r];
        int row = ib + quad*4 + r;
#pragma unroll
        for (int dt = 0; dt < 8; ++dt)
            O[(size_t)row*2048 + h*HDIM + dt*16 + l15] = __float2bfloat16(o[dt][r] * inv);
    }
}

// ---------------------------------------------------------------------------
extern "C" void kernel_launch(void* const* d_in, const int* in_sizes, int n_in,
                              void* d_out, int out_size, void* d_ws, size_t ws_size,
                              hipStream_t stream)
{
    (void)in_sizes; (void)n_in; (void)out_size; (void)ws_size;
    const float* hs   = (const float*)d_in[0];
    const float* cosb = (const float*)d_in[1];
    const float* sinb = (const float*)d_in[2];
    const float* Wq   = (const float*)d_in[3];
    const float* Wk   = (const float*)d_in[4];
    const float* Wv   = (const float*)d_in[5];
    const float* Wo   = (const float*)d_in[6];
    const float* qs   = (const float*)d_in[7];
    const float* ks   = (const float*)d_in[8];

    char* ws = (char*)d_ws;
    __hip_bfloat16* WqkvT = (__hip_bfloat16*)(ws);
    __hip_bfloat16* WoT   = (__hip_bfloat16*)(ws + (16u << 20));
    __hip_bfloat16* QKV   = (__hip_bfloat16*)(ws + (24u << 20));
    __hip_bfloat16* Qn    = (__hip_bfloat16*)(ws + (40u << 20));
    __hip_bfloat16* Kn    = (__hip_bfloat16*)(ws + (48u << 20));
    __hip_bfloat16* Vt    = (__hip_bfloat16*)(ws + (52u << 20));
    __hip_bfloat16* hsb   = (__hip_bfloat16*)(ws + (56u << 20)); // overlaid with AT
    __hip_bfloat16* AT    = (__hip_bfloat16*)(ws + (56u << 20)); // disjoint liveness

    cvt_hs_kernel<<<dim3(2048), dim3(256), 0, stream>>>(hs, hsb);
    transpose_w_kernel<<<dim3(3072), dim3(256), 0, stream>>>(Wq, Wk, Wv, Wo, WqkvT, WoT);
    gemm_bt_kernel<__hip_bfloat16><<<dim3(32, 16), dim3(256), 0, stream>>>(hsb, WqkvT, QKV, 2048, 4096, 2048);
    rmsrope_kernel<<<dim3(2048), dim3(256), 0, stream>>>(QKV, cosb, sinb, qs, ks, Qn, Kn);
    vtrans_kernel<<<dim3(32, 16), dim3(256), 0, stream>>>(QKV, Vt);
    attn_kernel<<<dim3(16, 32), dim3(256), 0, stream>>>(Qn, Kn, Vt, AT);
    gemm_bt_kernel<float><<<dim3(16, 16), dim3(256), 0, stream>>>(AT, WoT, (float*)d_out, 2048, 2048, 2048);
}

// Round 3
// 332.694 us; speedup vs baseline: 1.1006x; 1.1006x over previous
//
#include <hip/hip_runtime.h>
#include <hip/hip_bf16.h>
#include <cmath>

// I/O: all inputs float32 (per reference setup_inputs), output float32.
// Internal compute: bf16 MFMA with fp32 accumulation.
//
// Workspace layout (64 MB total):
//  [0,16M)   WqkvT  [4096][2048] bf16   (rows: 0-2047 WqT, 2048-3071 WkT, 3072-4095 WvT)
//  [16,24M)  WoT    [2048][2048] bf16
//  [24,40M)  QKVraw [2048][4096] bf16
//  [40,48M)  Qn     [2048][2048] bf16   (post rms+rope, pre-scaled by QK_SCALE)
//  [48,52M)  Kn     [2048][1024] bf16
//  [52,56M)  Vt     [1024][2048] bf16   ([hkv*128 d][s])
//  [56,64M)  hsb    [2048][2048] bf16   (live: kernels 1-2)   }  overlaid,
//  [56,64M)  AT     [2048][2048] bf16   (live: kernels 6-7)   }  disjoint liveness

typedef __bf16 bf16x8 __attribute__((ext_vector_type(8)));
typedef float  f32x4  __attribute__((ext_vector_type(4)));

#define S_LEN    2048
#define NH       16
#define NKV      8
#define HDIM     128
#define WIN      1024
#define QK_SCALE 0.08838834764831845f
#define RMS_EPS  1e-6f

__device__ __forceinline__ void gld16(void* lds, const void* g) {
    __builtin_amdgcn_global_load_lds(
        (const __attribute__((address_space(1))) unsigned int*)g,
        (__attribute__((address_space(3))) unsigned int*)lds, 16, 0, 0);
}

__device__ __forceinline__ unsigned short f2bu(float x) {
    __hip_bfloat16 h = __float2bfloat16(x);
    return *(unsigned short*)&h;
}

// ---------------------------------------------------------------------------
// hidden_states f32 -> bf16, 8 elems/thread
// ---------------------------------------------------------------------------
__global__ __launch_bounds__(256) void cvt_hs_kernel(
    const float* __restrict__ src, __hip_bfloat16* __restrict__ dst)
{
    size_t i = ((size_t)blockIdx.x * 256 + threadIdx.x) * 8;
    float4 a = *(const float4*)(src + i);
    float4 b = *(const float4*)(src + i + 4);
    unsigned short u[8] = { f2bu(a.x), f2bu(a.y), f2bu(a.z), f2bu(a.w),
                            f2bu(b.x), f2bu(b.y), f2bu(b.z), f2bu(b.w) };
    *(uint4*)(dst + i) = *(uint4*)u;
}

// ---------------------------------------------------------------------------
// Weight transpose + f32->bf16: W[K][N] f32 -> WT[N][K] bf16, 64x64 tiles.
// ---------------------------------------------------------------------------
__global__ __launch_bounds__(256) void transpose_w_kernel(
    const float* __restrict__ Wq, const float* __restrict__ Wk,
    const float* __restrict__ Wv, const float* __restrict__ Wo,
    __hip_bfloat16* __restrict__ WqkvT, __hip_bfloat16* __restrict__ WoT)
{
    __shared__ __attribute__((aligned(16))) unsigned short tile[64][72]; // 144B rows, 16B-aligned
    int id = blockIdx.x;
    const float* src; __hip_bfloat16* dst; int N, kt, nt;
    if (id < 1024)      { src = Wq; dst = WqkvT;                          N = 2048; kt = id >> 5;          nt = id & 31; }
    else if (id < 1536) { src = Wk; dst = WqkvT + (size_t)2048*2048;      N = 1024; kt = (id-1024) >> 4;   nt = (id-1024) & 15; }
    else if (id < 2048) { src = Wv; dst = WqkvT + (size_t)3072*2048;      N = 1024; kt = (id-1536) >> 4;   nt = (id-1536) & 15; }
    else                { src = Wo; dst = WoT;                            N = 2048; kt = (id-2048) >> 5;   nt = (id-2048) & 31; }
    int k0 = kt * 64, n0 = nt * 64;
    int tid = threadIdx.x;
#pragma unroll
    for (int p = 0; p < 2; ++p) {
        int c = p*256 + tid; int r = c >> 3, cc = (c & 7) * 8;
        const float* s = src + (size_t)(k0 + r)*N + n0 + cc;
        float4 a = *(const float4*)s;
        float4 b = *(const float4*)(s + 4);
        unsigned short u[8] = { f2bu(a.x), f2bu(a.y), f2bu(a.z), f2bu(a.w),
                                f2bu(b.x), f2bu(b.y), f2bu(b.z), f2bu(b.w) };
        *(uint4*)&tile[r][cc] = *(uint4*)u;
    }
    __syncthreads();
#pragma unroll
    for (int p = 0; p < 2; ++p) {
        int c = p*256 + tid; int r2 = c >> 3, c2 = (c & 7) * 8;
        uint4 o;
        o.x = tile[c2+0][r2] | ((unsigned)tile[c2+1][r2] << 16);
        o.y = tile[c2+2][r2] | ((unsigned)tile[c2+3][r2] << 16);
        o.z = tile[c2+4][r2] | ((unsigned)tile[c2+5][r2] << 16);
        o.w = tile[c2+6][r2] | ((unsigned)tile[c2+7][r2] << 16);
        *(uint4*)(dst + (size_t)(n0 + r2)*2048 + k0 + c2) = o;
    }
}

// ---------------------------------------------------------------------------
// V transpose: QKVraw[s][3072 + v] bf16 -> Vt[v][s] bf16
// ---------------------------------------------------------------------------
__global__ __launch_bounds__(256) void vtrans_kernel(
    const __hip_bfloat16* __restrict__ qkv, __hip_bfloat16* __restrict__ Vt)
{
    __shared__ __attribute__((aligned(16))) unsigned short tile[64][72];
    int s0 = blockIdx.x * 64;
    int v0 = blockIdx.y * 64;
    int tid = threadIdx.x;
#pragma unroll
    for (int p = 0; p < 2; ++p) {
        int c = p*256 + tid; int r = c >> 3, cc = (c & 7) * 8;
        uint4 v = *(const uint4*)(qkv + (size_t)(s0 + r)*4096 + 3072 + v0 + cc);
        *(uint4*)&tile[r][cc] = v;
    }
    __syncthreads();
#pragma unroll
    for (int p = 0; p < 2; ++p) {
        int c = p*256 + tid; int r2 = c >> 3, c2 = (c & 7) * 8;
        uint4 o;
        o.x = tile[c2+0][r2] | ((unsigned)tile[c2+1][r2] << 16);
        o.y = tile[c2+2][r2] | ((unsigned)tile[c2+3][r2] << 16);
        o.z = tile[c2+4][r2] | ((unsigned)tile[c2+5][r2] << 16);
        o.w = tile[c2+6][r2] | ((unsigned)tile[c2+7][r2] << 16);
        *(uint4*)(Vt + (size_t)(v0 + r2)*2048 + s0 + c2) = o;
    }
}

// ---------------------------------------------------------------------------
// GEMM: C[M][N] = A[M][K] * BT[N][K]^T.  128x128 tile, BK=32, 4 waves (2x2),
// global_load_lds staging, mfma_f32_16x16x32_bf16 (m97 structure).
// ---------------------------------------------------------------------------
template <typename OT>
__global__ __launch_bounds__(256) void gemm_bt_kernel(
    const __hip_bfloat16* __restrict__ A, const __hip_bfloat16* __restrict__ BT,
    OT* __restrict__ C, int M, int N, int K)
{
    __shared__ __attribute__((aligned(16))) __hip_bfloat16 As[128*32];
    __shared__ __attribute__((aligned(16))) __hip_bfloat16 Bs[128*32];
    const int tid  = threadIdx.x;
    const int lane = tid & 63;
    const int wave = tid >> 6;
    const int quad = lane >> 4, l15 = lane & 15;
    const int m0 = blockIdx.y * 128, n0 = blockIdx.x * 128;
    const int wm = (wave >> 1) * 64, wn = (wave & 1) * 64;

    f32x4 acc[4][4] = {};

    for (int k0 = 0; k0 < K; k0 += 32) {
#pragma unroll
        for (int p = 0; p < 2; ++p) {
            int c = p*256 + tid;
            int row = c >> 2, seg = c & 3;
            gld16((char*)As + c*16, A  + (size_t)(m0 + row)*K + k0 + seg*8);
            gld16((char*)Bs + c*16, BT + (size_t)(n0 + row)*K + k0 + seg*8);
        }
        __syncthreads();
        bf16x8 af[4], bfr[4];
#pragma unroll
        for (int t = 0; t < 4; ++t) {
            af[t]  = *(const bf16x8*)(As + (wm + t*16 + l15)*32 + quad*8);
            bfr[t] = *(const bf16x8*)(Bs + (wn + t*16 + l15)*32 + quad*8);
        }
#pragma unroll
        for (int mt = 0; mt < 4; ++mt)
#pragma unroll
            for (int nt = 0; nt < 4; ++nt)
                acc[mt][nt] = __builtin_amdgcn_mfma_f32_16x16x32_bf16(af[mt], bfr[nt], acc[mt][nt], 0, 0, 0);
        __syncthreads();
    }
#pragma unroll
    for (int mt = 0; mt < 4; ++mt)
#pragma unroll
        for (int nt = 0; nt < 4; ++nt)
#pragma unroll
            for (int r = 0; r < 4; ++r) {
                int row = m0 + wm + mt*16 + quad*4 + r;
                int col = n0 + wn + nt*16 + l15;
                if constexpr (__is_same(OT, float))
                    C[(size_t)row*N + col] = acc[mt][nt][r];
                else
                    C[(size_t)row*N + col] = __float2bfloat16(acc[mt][nt][r]);
            }
}

// ---------------------------------------------------------------------------
// RMSNorm + RoPE on Q and K rows of QKVraw. Block per s; wave per head-unit.
// Q output is pre-scaled by QK_SCALE (folded out of the attention kernel).
// ---------------------------------------------------------------------------
__global__ __launch_bounds__(256) void rmsrope_kernel(
    const __hip_bfloat16* __restrict__ qkv,
    const float* __restrict__ cosb, const float* __restrict__ sinb,
    const float* __restrict__ qsc,  const float* __restrict__ ksc,
    __hip_bfloat16* __restrict__ Qn, __hip_bfloat16* __restrict__ Kn)
{
    int s = blockIdx.x;
    int wave = threadIdx.x >> 6, lane = threadIdx.x & 63;
    float c1 = cosb[s*128 + lane];
    float c2 = cosb[s*128 + 64 + lane];
    float s1 = sinb[s*128 + lane];
    float s2 = sinb[s*128 + 64 + lane];
    for (int u = wave; u < 24; u += 4) {
        bool isq = (u < 16);
        int h = isq ? u : u - 16;
        const __hip_bfloat16* x = qkv + (size_t)s*4096 + (isq ? h*128 : 2048 + h*128);
        float x1 = (float)x[lane], x2 = (float)x[lane + 64];
        float ss = x1*x1 + x2*x2;
#pragma unroll
        for (int off = 32; off; off >>= 1) ss += __shfl_xor(ss, off);
        float r = rsqrtf(ss * (1.0f/128.0f) + RMS_EPS);
        if (isq) r *= QK_SCALE;            // fold attention scale into Q
        const float* sc = isq ? qsc : ksc;
        float y1 = x1 * r * sc[lane];
        float y2 = x2 * r * sc[lane + 64];
        float o1 = y1*c1 - y2*s1;   // d < 64:  x*c - x[d+64]*s
        float o2 = y2*c2 + y1*s2;   // d >= 64: x*c + x[d-64]*s
        __hip_bfloat16* dst = isq ? (Qn + (size_t)s*2048 + h*128)
                                  : (Kn + (size_t)s*1024 + h*128);
        dst[lane]      = __float2bfloat16(o1);
        dst[lane + 64] = __float2bfloat16(o2);
    }
}

// ---------------------------------------------------------------------------
// Flash attention, sliding-window causal.  ONE WAVE PER BLOCK (64 thr):
// no barriers ever (P round-trip is per-wave, lgkmcnt-ordered), 2048 blocks
// for backfill load-balance, descending-work dispatch order, V-loads issued
// before softmax to hide L2 latency under the exp/shuffle chain.
// Wave owns 16 q-rows (ib..ib+15) of head h; j-tiles of 64 keys.
// ---------------------------------------------------------------------------
__global__ __launch_bounds__(64) void attn_kernel(
    const __hip_bfloat16* __restrict__ Qn,  // [S][2048], pre-scaled
    const __hip_bfloat16* __restrict__ Kn,  // [S][1024]
    const __hip_bfloat16* __restrict__ Vt,  // [1024][S]
    __hip_bfloat16* __restrict__ O)         // [S][2048]
{
    __shared__ __attribute__((aligned(16))) __hip_bfloat16 P[16][72];
    const int bx   = blockIdx.x;
    const int h    = bx & 15;
    const int ib   = (127 - (bx >> 4)) * 16;   // descending work order
    const int hk   = h >> 1;
    const int lane = threadIdx.x;
    const int quad = lane >> 4, l15 = lane & 15;

    bf16x8 qf[4];
    const __hip_bfloat16* qbase = Qn + (size_t)(ib + l15)*2048 + h*HDIM + quad*8;
#pragma unroll
    for (int kk = 0; kk < 4; ++kk) qf[kk] = *(const bf16x8*)(qbase + kk*32);

    f32x4 o[8] = {};
    float mrow[4], lrow[4];
#pragma unroll
    for (int r = 0; r < 4; ++r) { mrow[r] = -INFINITY; lrow[r] = 0.f; }

    int j_lo = ib - WIN; if (j_lo < 0) j_lo = 0;
    const int jstart = (j_lo >> 6) << 6;
    const int jend   = (ib >> 6) << 6;

    for (int j0 = jstart; j0 <= jend; j0 += 64) {
        // ---- batch-issue all 16 K fragment loads (independent) ----
        bf16x8 kf[16];
#pragma unroll
        for (int nt = 0; nt < 4; ++nt) {
            const __hip_bfloat16* kb = Kn + (size_t)(j0 + nt*16 + l15)*1024 + hk*HDIM + quad*8;
#pragma unroll
            for (int kk = 0; kk < 4; ++kk)
                kf[nt*4+kk] = *(const bf16x8*)(kb + kk*32);
        }
        // ---- S = Q K^T (16 x 64) ----
        f32x4 sacc[4] = {};
#pragma unroll
        for (int nt = 0; nt < 4; ++nt)
#pragma unroll
            for (int kk = 0; kk < 4; ++kk)
                sacc[nt] = __builtin_amdgcn_mfma_f32_16x16x32_bf16(qf[kk], kf[nt*4+kk], sacc[nt], 0, 0, 0);

        // ---- batch-issue V fragment loads NOW (latency hides under softmax) ----
        bf16x8 vf[16];
#pragma unroll
        for (int ks = 0; ks < 2; ++ks)
#pragma unroll
            for (int dt = 0; dt < 8; ++dt)
                vf[ks*8+dt] = *(const bf16x8*)(Vt + (size_t)(hk*HDIM + dt*16 + l15)*2048 + j0 + ks*32 + quad*8);

        // ---- mask (only boundary tiles), online softmax ----
        float sval[4][4];
        float tmax[4] = {-INFINITY, -INFINITY, -INFINITY, -INFINITY};
        const bool need_mask = (j0 + 63 > ib) || (j0 < ib + 15 - WIN);
        if (need_mask) {
#pragma unroll
            for (int nt = 0; nt < 4; ++nt) {
                int j = j0 + nt*16 + l15;
#pragma unroll
                for (int r = 0; r < 4; ++r) {
                    int i = ib + quad*4 + r;
                    bool valid = (j <= i) && (i - j <= WIN);
                    float sv = valid ? sacc[nt][r] : -INFINITY;
                    sval[nt][r] = sv;
                    tmax[r] = fmaxf(tmax[r], sv);
                }
            }
        } else {
#pragma unroll
            for (int nt = 0; nt < 4; ++nt)
#pragma unroll
                for (int r = 0; r < 4; ++r) {
                    float sv = sacc[nt][r];
                    sval[nt][r] = sv;
                    tmax[r] = fmaxf(tmax[r], sv);
                }
        }
#pragma unroll
        for (int r = 0; r < 4; ++r) {
            tmax[r] = fmaxf(tmax[r], __shfl_xor(tmax[r], 1));
            tmax[r] = fmaxf(tmax[r], __shfl_xor(tmax[r], 2));
            tmax[r] = fmaxf(tmax[r], __shfl_xor(tmax[r], 4));
            tmax[r] = fmaxf(tmax[r], __shfl_xor(tmax[r], 8));
        }
        float alpha[4], rsum[4];
#pragma unroll
        for (int r = 0; r < 4; ++r) {
            float mnew = fmaxf(mrow[r], tmax[r]);
            alpha[r] = (mrow[r] == -INFINITY) ? 0.f : __expf(mrow[r] - mnew);
            mrow[r] = mnew;
            rsum[r] = 0.f;
        }
#pragma unroll
        for (int nt = 0; nt < 4; ++nt)
#pragma unroll
            for (int r = 0; r < 4; ++r) {
                float p = (sval[nt][r] == -INFINITY) ? 0.f : __expf(sval[nt][r] - mrow[r]);
                rsum[r] += p;
                P[quad*4 + r][nt*16 + l15] = __float2bfloat16(p);
            }
#pragma unroll
        for (int r = 0; r < 4; ++r) {
            rsum[r] += __shfl_xor(rsum[r], 1);
            rsum[r] += __shfl_xor(rsum[r], 2);
            rsum[r] += __shfl_xor(rsum[r], 4);
            rsum[r] += __shfl_xor(rsum[r], 8);
            lrow[r] = lrow[r]*alpha[r] + rsum[r];
#pragma unroll
            for (int dt = 0; dt < 8; ++dt) o[dt][r] *= alpha[r];
        }
        // ---- O += P V  (P read is same-wave, ordered by lgkmcnt; no barrier) ----
#pragma unroll
        for (int ks = 0; ks < 2; ++ks) {
            bf16x8 pf = *(const bf16x8*)&P[l15][ks*32 + quad*8];
#pragma unroll
            for (int dt = 0; dt < 8; ++dt)
                o[dt] = __builtin_amdgcn_mfma_f32_16x16x32_bf16(pf, vf[ks*8+dt], o[dt], 0, 0, 0);
        }
    }
    // ---- epilogue ----
#pragma unroll
    for (int r = 0; r < 4; ++r) {
        float inv = 1.0f / lrow[r];
        int row = ib + quad*4 + r;
#pragma unroll
        for (int dt = 0; dt < 8; ++dt)
            O[(size_t)row*2048 + h*HDIM + dt*16 + l15] = __float2bfloat16(o[dt][r] * inv);
    }
}

// ---------------------------------------------------------------------------
extern "C" void kernel_launch(void* const* d_in, const int* in_sizes, int n_in,
                              void* d_out, int out_size, void* d_ws, size_t ws_size,
                              hipStream_t stream)
{
    (void)in_sizes; (void)n_in; (void)out_size; (void)ws_size;
    const float* hs   = (const float*)d_in[0];
    const float* cosb = (const float*)d_in[1];
    const float* sinb = (const float*)d_in[2];
    const float* Wq   = (const float*)d_in[3];
    const float* Wk   = (const float*)d_in[4];
    const float* Wv   = (const float*)d_in[5];
    const float* Wo   = (const float*)d_in[6];
    const float* qs   = (const float*)d_in[7];
    const float* ks   = (const float*)d_in[8];

    char* ws = (char*)d_ws;
    __hip_bfloat16* WqkvT = (__hip_bfloat16*)(ws);
    __hip_bfloat16* WoT   = (__hip_bfloat16*)(ws + (16u << 20));
    __hip_bfloat16* QKV   = (__hip_bfloat16*)(ws + (24u << 20));
    __hip_bfloat16* Qn    = (__hip_bfloat16*)(ws + (40u << 20));
    __hip_bfloat16* Kn    = (__hip_bfloat16*)(ws + (48u << 20));
    __hip_bfloat16* Vt    = (__hip_bfloat16*)(ws + (52u << 20));
    __hip_bfloat16* hsb   = (__hip_bfloat16*)(ws + (56u << 20)); // overlaid with AT
    __hip_bfloat16* AT    = (__hip_bfloat16*)(ws + (56u << 20)); // disjoint liveness

    cvt_hs_kernel<<<dim3(2048), dim3(256), 0, stream>>>(hs, hsb);
    transpose_w_kernel<<<dim3(3072), dim3(256), 0, stream>>>(Wq, Wk, Wv, Wo, WqkvT, WoT);
    gemm_bt_kernel<__hip_bfloat16><<<dim3(32, 16), dim3(256), 0, stream>>>(hsb, WqkvT, QKV, 2048, 4096, 2048);
    rmsrope_kernel<<<dim3(2048), dim3(256), 0, stream>>>(QKV, cosb, sinb, qs, ks, Qn, Kn);
    vtrans_kernel<<<dim3(32, 16), dim3(256), 0, stream>>>(QKV, Vt);
    attn_kernel<<<dim3(2048), dim3(64), 0, stream>>>(Qn, Kn, Vt, AT);
    gemm_bt_kernel<float><<<dim3(16, 16), dim3(256), 0, stream>>>(AT, WoT, (float*)d_out, 2048, 2048, 2048);
}

// Round 4
// 332.215 us; speedup vs baseline: 1.1022x; 1.0014x over previous
//
#include <hip/hip_runtime.h>
#include <hip/hip_bf16.h>
#include <cmath>

// I/O: all inputs float32 (per reference setup_inputs), output float32.
// Internal compute: bf16 MFMA with fp32 accumulation.
//
// Workspace layout (64 MB total):
//  [0,16M)   WqkvT  [4096][2048] bf16   (rows: 0-2047 WqT, 2048-3071 WkT, 3072-4095 WvT)
//  [16,24M)  WoT    [2048][2048] bf16
//  [24,40M)  QKVraw [2048][4096] bf16
//  [40,48M)  Qn     [2048][2048] bf16   (post rms+rope, pre-scaled by QK_SCALE*log2e)
//  [48,52M)  Kn     [2048][1024] bf16
//  [52,56M)  Vt     [1024][2048] bf16   ([hkv*128 d][s])
//  [56,64M)  hsb    [2048][2048] bf16   (live: kernels 1-2)   }  overlaid,
//  [56,64M)  AT     [2048][2048] bf16   (live: kernels 6-7)   }  disjoint liveness

typedef __bf16 bf16x8 __attribute__((ext_vector_type(8)));
typedef float  f32x4  __attribute__((ext_vector_type(4)));

#define S_LEN    2048
#define NH       16
#define NKV      8
#define HDIM     128
#define WIN      1024
// QK_SCALE * log2(e): scores computed directly in log2 domain -> exp2
#define QK_SCALE_L2E 0.12751744595f
#define RMS_EPS  1e-6f

__device__ __forceinline__ void gld16(void* lds, const void* g) {
    __builtin_amdgcn_global_load_lds(
        (const __attribute__((address_space(1))) unsigned int*)g,
        (__attribute__((address_space(3))) unsigned int*)lds, 16, 0, 0);
}

__device__ __forceinline__ unsigned short f2bu(float x) {
    __hip_bfloat16 h = __float2bfloat16(x);
    return *(unsigned short*)&h;
}

// ---------------------------------------------------------------------------
// hidden_states f32 -> bf16, 8 elems/thread
// ---------------------------------------------------------------------------
__global__ __launch_bounds__(256) void cvt_hs_kernel(
    const float* __restrict__ src, __hip_bfloat16* __restrict__ dst)
{
    size_t i = ((size_t)blockIdx.x * 256 + threadIdx.x) * 8;
    float4 a = *(const float4*)(src + i);
    float4 b = *(const float4*)(src + i + 4);
    unsigned short u[8] = { f2bu(a.x), f2bu(a.y), f2bu(a.z), f2bu(a.w),
                            f2bu(b.x), f2bu(b.y), f2bu(b.z), f2bu(b.w) };
    *(uint4*)(dst + i) = *(uint4*)u;
}

// ---------------------------------------------------------------------------
// Weight transpose + f32->bf16: W[K][N] f32 -> WT[N][K] bf16, 64x64 tiles.
// ---------------------------------------------------------------------------
__global__ __launch_bounds__(256) void transpose_w_kernel(
    const float* __restrict__ Wq, const float* __restrict__ Wk,
    const float* __restrict__ Wv, const float* __restrict__ Wo,
    __hip_bfloat16* __restrict__ WqkvT, __hip_bfloat16* __restrict__ WoT)
{
    __shared__ __attribute__((aligned(16))) unsigned short tile[64][72]; // 144B rows, 16B-aligned
    int id = blockIdx.x;
    const float* src; __hip_bfloat16* dst; int N, kt, nt;
    if (id < 1024)      { src = Wq; dst = WqkvT;                          N = 2048; kt = id >> 5;          nt = id & 31; }
    else if (id < 1536) { src = Wk; dst = WqkvT + (size_t)2048*2048;      N = 1024; kt = (id-1024) >> 4;   nt = (id-1024) & 15; }
    else if (id < 2048) { src = Wv; dst = WqkvT + (size_t)3072*2048;      N = 1024; kt = (id-1536) >> 4;   nt = (id-1536) & 15; }
    else                { src = Wo; dst = WoT;                            N = 2048; kt = (id-2048) >> 5;   nt = (id-2048) & 31; }
    int k0 = kt * 64, n0 = nt * 64;
    int tid = threadIdx.x;
#pragma unroll
    for (int p = 0; p < 2; ++p) {
        int c = p*256 + tid; int r = c >> 3, cc = (c & 7) * 8;
        const float* s = src + (size_t)(k0 + r)*N + n0 + cc;
        float4 a = *(const float4*)s;
        float4 b = *(const float4*)(s + 4);
        unsigned short u[8] = { f2bu(a.x), f2bu(a.y), f2bu(a.z), f2bu(a.w),
                                f2bu(b.x), f2bu(b.y), f2bu(b.z), f2bu(b.w) };
        *(uint4*)&tile[r][cc] = *(uint4*)u;
    }
    __syncthreads();
#pragma unroll
    for (int p = 0; p < 2; ++p) {
        int c = p*256 + tid; int r2 = c >> 3, c2 = (c & 7) * 8;
        uint4 o;
        o.x = tile[c2+0][r2] | ((unsigned)tile[c2+1][r2] << 16);
        o.y = tile[c2+2][r2] | ((unsigned)tile[c2+3][r2] << 16);
        o.z = tile[c2+4][r2] | ((unsigned)tile[c2+5][r2] << 16);
        o.w = tile[c2+6][r2] | ((unsigned)tile[c2+7][r2] << 16);
        *(uint4*)(dst + (size_t)(n0 + r2)*2048 + k0 + c2) = o;
    }
}

// ---------------------------------------------------------------------------
// V transpose: QKVraw[s][3072 + v] bf16 -> Vt[v][s] bf16
// ---------------------------------------------------------------------------
__global__ __launch_bounds__(256) void vtrans_kernel(
    const __hip_bfloat16* __restrict__ qkv, __hip_bfloat16* __restrict__ Vt)
{
    __shared__ __attribute__((aligned(16))) unsigned short tile[64][72];
    int s0 = blockIdx.x * 64;
    int v0 = blockIdx.y * 64;
    int tid = threadIdx.x;
#pragma unroll
    for (int p = 0; p < 2; ++p) {
        int c = p*256 + tid; int r = c >> 3, cc = (c & 7) * 8;
        uint4 v = *(const uint4*)(qkv + (size_t)(s0 + r)*4096 + 3072 + v0 + cc);
        *(uint4*)&tile[r][cc] = v;
    }
    __syncthreads();
#pragma unroll
    for (int p = 0; p < 2; ++p) {
        int c = p*256 + tid; int r2 = c >> 3, c2 = (c & 7) * 8;
        uint4 o;
        o.x = tile[c2+0][r2] | ((unsigned)tile[c2+1][r2] << 16);
        o.y = tile[c2+2][r2] | ((unsigned)tile[c2+3][r2] << 16);
        o.z = tile[c2+4][r2] | ((unsigned)tile[c2+5][r2] << 16);
        o.w = tile[c2+6][r2] | ((unsigned)tile[c2+7][r2] << 16);
        *(uint4*)(Vt + (size_t)(v0 + r2)*2048 + s0 + c2) = o;
    }
}

// ---------------------------------------------------------------------------
// GEMM: C[M][N] = A[M][K] * BT[N][K]^T.  128x128 tile, BK=32, 4 waves (2x2),
// global_load_lds staging, mfma_f32_16x16x32_bf16 (m97 structure).
// ---------------------------------------------------------------------------
template <typename OT>
__global__ __launch_bounds__(256) void gemm_bt_kernel(
    const __hip_bfloat16* __restrict__ A, const __hip_bfloat16* __restrict__ BT,
    OT* __restrict__ C, int M, int N, int K)
{
    __shared__ __attribute__((aligned(16))) __hip_bfloat16 As[128*32];
    __shared__ __attribute__((aligned(16))) __hip_bfloat16 Bs[128*32];
    const int tid  = threadIdx.x;
    const int lane = tid & 63;
    const int wave = tid >> 6;
    const int quad = lane >> 4, l15 = lane & 15;
    const int m0 = blockIdx.y * 128, n0 = blockIdx.x * 128;
    const int wm = (wave >> 1) * 64, wn = (wave & 1) * 64;

    f32x4 acc[4][4] = {};

    for (int k0 = 0; k0 < K; k0 += 32) {
#pragma unroll
        for (int p = 0; p < 2; ++p) {
            int c = p*256 + tid;
            int row = c >> 2, seg = c & 3;
            gld16((char*)As + c*16, A  + (size_t)(m0 + row)*K + k0 + seg*8);
            gld16((char*)Bs + c*16, BT + (size_t)(n0 + row)*K + k0 + seg*8);
        }
        __syncthreads();
        bf16x8 af[4], bfr[4];
#pragma unroll
        for (int t = 0; t < 4; ++t) {
            af[t]  = *(const bf16x8*)(As + (wm + t*16 + l15)*32 + quad*8);
            bfr[t] = *(const bf16x8*)(Bs + (wn + t*16 + l15)*32 + quad*8);
        }
#pragma unroll
        for (int mt = 0; mt < 4; ++mt)
#pragma unroll
            for (int nt = 0; nt < 4; ++nt)
                acc[mt][nt] = __builtin_amdgcn_mfma_f32_16x16x32_bf16(af[mt], bfr[nt], acc[mt][nt], 0, 0, 0);
        __syncthreads();
    }
#pragma unroll
    for (int mt = 0; mt < 4; ++mt)
#pragma unroll
        for (int nt = 0; nt < 4; ++nt)
#pragma unroll
            for (int r = 0; r < 4; ++r) {
                int row = m0 + wm + mt*16 + quad*4 + r;
                int col = n0 + wn + nt*16 + l15;
                if constexpr (__is_same(OT, float))
                    C[(size_t)row*N + col] = acc[mt][nt][r];
                else
                    C[(size_t)row*N + col] = __float2bfloat16(acc[mt][nt][r]);
            }
}

// ---------------------------------------------------------------------------
// RMSNorm + RoPE on Q and K rows of QKVraw. Block per s; wave per head-unit.
// Q output is pre-scaled by QK_SCALE*log2(e) (attention uses exp2 directly).
// ---------------------------------------------------------------------------
__global__ __launch_bounds__(256) void rmsrope_kernel(
    const __hip_bfloat16* __restrict__ qkv,
    const float* __restrict__ cosb, const float* __restrict__ sinb,
    const float* __restrict__ qsc,  const float* __restrict__ ksc,
    __hip_bfloat16* __restrict__ Qn, __hip_bfloat16* __restrict__ Kn)
{
    int s = blockIdx.x;
    int wave = threadIdx.x >> 6, lane = threadIdx.x & 63;
    float c1 = cosb[s*128 + lane];
    float c2 = cosb[s*128 + 64 + lane];
    float s1 = sinb[s*128 + lane];
    float s2 = sinb[s*128 + 64 + lane];
    for (int u = wave; u < 24; u += 4) {
        bool isq = (u < 16);
        int h = isq ? u : u - 16;
        const __hip_bfloat16* x = qkv + (size_t)s*4096 + (isq ? h*128 : 2048 + h*128);
        float x1 = (float)x[lane], x2 = (float)x[lane + 64];
        float ss = x1*x1 + x2*x2;
#pragma unroll
        for (int off = 32; off; off >>= 1) ss += __shfl_xor(ss, off);
        float r = rsqrtf(ss * (1.0f/128.0f) + RMS_EPS);
        if (isq) r *= QK_SCALE_L2E;        // fold attn scale + log2e into Q
        const float* sc = isq ? qsc : ksc;
        float y1 = x1 * r * sc[lane];
        float y2 = x2 * r * sc[lane + 64];
        float o1 = y1*c1 - y2*s1;   // d < 64:  x*c - x[d+64]*s
        float o2 = y2*c2 + y1*s2;   // d >= 64: x*c + x[d-64]*s
        __hip_bfloat16* dst = isq ? (Qn + (size_t)s*2048 + h*128)
                                  : (Kn + (size_t)s*1024 + h*128);
        dst[lane]      = __float2bfloat16(o1);
        dst[lane + 64] = __float2bfloat16(o2);
    }
}

// ---------------------------------------------------------------------------
// Flash attention, sliding-window causal.  One wave per block.
// Key design points (round-4):
//  * __launch_bounds__(64,2): 256-VGPR budget so all 32 K/V fragment loads
//    are simultaneously in flight (VGPR 124 cap had serialized them).
//  * NO online max: scores bounded (|q||k|*scale <= ~26 in log2 domain),
//    p = exp2(s) directly; per-lane lrow accumulation; single cross-lane
//    reduce in the epilogue. Zero per-tile shuffle waits.
//  * K(t+1) prefetch issued between P-write and P-read (vmcnt independent
//    of the lgkmcnt the P read waits on).
//  * P padded [16][76]: quad row-stride 608B = 24 dwords mod 32 -> write
//    banks fully spread (removes the old 4-way conflict).
// ---------------------------------------------------------------------------
__global__ __launch_bounds__(64, 2) void attn_kernel(
    const __hip_bfloat16* __restrict__ Qn,  // [S][2048], pre-scaled (log2 domain)
    const __hip_bfloat16* __restrict__ Kn,  // [S][1024]
    const __hip_bfloat16* __restrict__ Vt,  // [1024][S]
    __hip_bfloat16* __restrict__ O)         // [S][2048]
{
    __shared__ __attribute__((aligned(16))) __hip_bfloat16 P[16][76];
    const int bx   = blockIdx.x;
    const int h    = bx & 15;
    const int ib   = (127 - (bx >> 4)) * 16;   // long-window blocks first
    const int hk   = h >> 1;
    const int lane = threadIdx.x;
    const int quad = lane >> 4, l15 = lane & 15;

    bf16x8 qf[4];
    const __hip_bfloat16* qbase = Qn + (size_t)(ib + l15)*2048 + h*HDIM + quad*8;
#pragma unroll
    for (int kk = 0; kk < 4; ++kk) qf[kk] = *(const bf16x8*)(qbase + kk*32);

    f32x4 o[8] = {};
    float lrow[4] = {0.f, 0.f, 0.f, 0.f};

    int j_lo = ib - WIN; if (j_lo < 0) j_lo = 0;
    const int jstart = (j_lo >> 6) << 6;
    const int jend   = (ib >> 6) << 6;

    const __hip_bfloat16* kbase = Kn + hk*HDIM + quad*8;
    const __hip_bfloat16* vbase = Vt + (size_t)(hk*HDIM)*2048 + quad*8;

    // preload first K tile (16 independent b128 loads)
    bf16x8 kf[16];
#pragma unroll
    for (int nt = 0; nt < 4; ++nt)
#pragma unroll
        for (int kk = 0; kk < 4; ++kk)
            kf[nt*4+kk] = *(const bf16x8*)(kbase + (size_t)(jstart + nt*16 + l15)*1024 + kk*32);

    for (int j0 = jstart; j0 <= jend; j0 += 64) {
        // ---- S = Q K^T (16 x 64), log2 domain ----
        f32x4 sacc[4] = {};
#pragma unroll
        for (int nt = 0; nt < 4; ++nt)
#pragma unroll
            for (int kk = 0; kk < 4; ++kk)
                sacc[nt] = __builtin_amdgcn_mfma_f32_16x16x32_bf16(qf[kk], kf[nt*4+kk], sacc[nt], 0, 0, 0);

        // ---- V loads for this tile (latency hides under exp/P path) ----
        bf16x8 vf[16];
#pragma unroll
        for (int ks = 0; ks < 2; ++ks)
#pragma unroll
            for (int dt = 0; dt < 8; ++dt)
                vf[ks*8+dt] = *(const bf16x8*)(vbase + (size_t)(dt*16 + l15)*2048 + j0 + ks*32);

        // ---- p = exp2(s) (no max subtraction), P write, per-lane row-sum ----
        const bool need_mask = (j0 + 63 > ib) || (j0 < ib + 15 - WIN);
        if (need_mask) {
#pragma unroll
            for (int nt = 0; nt < 4; ++nt) {
                int j = j0 + nt*16 + l15;
#pragma unroll
                for (int r = 0; r < 4; ++r) {
                    int i = ib + quad*4 + r;
                    bool valid = (j <= i) && (i - j <= WIN);
                    float p = valid ? __builtin_exp2f(sacc[nt][r]) : 0.f;
                    lrow[r] += p;
                    P[quad*4 + r][nt*16 + l15] = __float2bfloat16(p);
                }
            }
        } else {
#pragma unroll
            for (int nt = 0; nt < 4; ++nt)
#pragma unroll
                for (int r = 0; r < 4; ++r) {
                    float p = __builtin_exp2f(sacc[nt][r]);
                    lrow[r] += p;
                    P[quad*4 + r][nt*16 + l15] = __float2bfloat16(p);
                }
        }

        // ---- prefetch next K tile (vmcnt; overlaps P lgkmcnt drain) ----
        if (j0 + 64 <= jend) {
#pragma unroll
            for (int nt = 0; nt < 4; ++nt)
#pragma unroll
                for (int kk = 0; kk < 4; ++kk)
                    kf[nt*4+kk] = *(const bf16x8*)(kbase + (size_t)(j0 + 64 + nt*16 + l15)*1024 + kk*32);
        }

        // ---- O += P V (P read is same-wave, lgkmcnt-ordered; no barrier) ----
#pragma unroll
        for (int ks = 0; ks < 2; ++ks) {
            bf16x8 pf = *(const bf16x8*)&P[l15][ks*32 + quad*8];
#pragma unroll
            for (int dt = 0; dt < 8; ++dt)
                o[dt] = __builtin_amdgcn_mfma_f32_16x16x32_bf16(pf, vf[ks*8+dt], o[dt], 0, 0, 0);
        }
    }

    // ---- epilogue: single cross-lane reduce of lrow, normalize, store ----
#pragma unroll
    for (int r = 0; r < 4; ++r) {
        lrow[r] += __shfl_xor(lrow[r], 1);
        lrow[r] += __shfl_xor(lrow[r], 2);
        lrow[r] += __shfl_xor(lrow[r], 4);
        lrow[r] += __shfl_xor(lrow[r], 8);
        float inv = 1.0f / lrow[r];
        int row = ib + quad*4 + r;
#pragma unroll
        for (int dt = 0; dt < 8; ++dt)
            O[(size_t)row*2048 + h*HDIM + dt*16 + l15] = __float2bfloat16(o[dt][r] * inv);
    }
}

// ---------------------------------------------------------------------------
extern "C" void kernel_launch(void* const* d_in, const int* in_sizes, int n_in,
                              void* d_out, int out_size, void* d_ws, size_t ws_size,
                              hipStream_t stream)
{
    (void)in_sizes; (void)n_in; (void)out_size; (void)ws_size;
    const float* hs   = (const float*)d_in[0];
    const float* cosb = (const float*)d_in[1];
    const float* sinb = (const float*)d_in[2];
    const float* Wq   = (const float*)d_in[3];
    const float* Wk   = (const float*)d_in[4];
    const float* Wv   = (const float*)d_in[5];
    const float* Wo   = (const float*)d_in[6];
    const float* qs   = (const float*)d_in[7];
    const float* ks   = (const float*)d_in[8];

    char* ws = (char*)d_ws;
    __hip_bfloat16* WqkvT = (__hip_bfloat16*)(ws);
    __hip_bfloat16* WoT   = (__hip_bfloat16*)(ws + (16u << 20));
    __hip_bfloat16* QKV   = (__hip_bfloat16*)(ws + (24u << 20));
    __hip_bfloat16* Qn    = (__hip_bfloat16*)(ws + (40u << 20));
    __hip_bfloat16* Kn    = (__hip_bfloat16*)(ws + (48u << 20));
    __hip_bfloat16* Vt    = (__hip_bfloat16*)(ws + (52u << 20));
    __hip_bfloat16* hsb   = (__hip_bfloat16*)(ws + (56u << 20)); // overlaid with AT
    __hip_bfloat16* AT    = (__hip_bfloat16*)(ws + (56u << 20)); // disjoint liveness

    cvt_hs_kernel<<<dim3(2048), dim3(256), 0, stream>>>(hs, hsb);
    transpose_w_kernel<<<dim3(3072), dim3(256), 0, stream>>>(Wq, Wk, Wv, Wo, WqkvT, WoT);
    gemm_bt_kernel<__hip_bfloat16><<<dim3(32, 16), dim3(256), 0, stream>>>(hsb, WqkvT, QKV, 2048, 4096, 2048);
    rmsrope_kernel<<<dim3(2048), dim3(256), 0, stream>>>(QKV, cosb, sinb, qs, ks, Qn, Kn);
    vtrans_kernel<<<dim3(32, 16), dim3(256), 0, stream>>>(QKV, Vt);
    attn_kernel<<<dim3(2048), dim3(64), 0, stream>>>(Qn, Kn, Vt, AT);
    gemm_bt_kernel<float><<<dim3(16, 16), dim3(256), 0, stream>>>(AT, WoT, (float*)d_out, 2048, 2048, 2048);
}

// Round 5
// 261.573 us; speedup vs baseline: 1.3998x; 1.2701x over previous
//
#include <hip/hip_runtime.h>
#include <hip/hip_bf16.h>
#include <cmath>

// I/O: all inputs float32 (per reference setup_inputs), output float32.
// Internal compute: bf16 MFMA with fp32 accumulation.
//
// Workspace layout (64 MB total):
//  [0,16M)   WqkvT  [4096][2048] bf16   (rows: 0-2047 WqT, 2048-3071 WkT, 3072-4095 WvT)
//  [16,24M)  WoT    [2048][2048] bf16
//  [24,40M)  QKVraw [2048][4096] bf16
//  [40,48M)  Qn     [2048][2048] bf16   (post rms+rope, pre-scaled by QK_SCALE*log2e)
//  [48,52M)  Kn     [2048][1024] bf16
//  [52,56M)  Vt     [1024][2048] bf16   ([hkv*128 d][s])
//  [56,64M)  hsb    [2048][2048] bf16   (live: kernels 1-2)   }  overlaid,
//  [56,64M)  AT     [2048][2048] bf16   (live: kernels 6-7)   }  disjoint liveness

typedef __bf16 bf16x8 __attribute__((ext_vector_type(8)));
typedef float  f32x4  __attribute__((ext_vector_type(4)));

#define S_LEN    2048
#define NH       16
#define NKV      8
#define HDIM     128
#define WIN      1024
// QK_SCALE * log2(e): scores computed directly in log2 domain -> exp2
#define QK_SCALE_L2E 0.12751744595f
#define RMS_EPS  1e-6f

__device__ __forceinline__ void gld16(void* lds, const void* g) {
    __builtin_amdgcn_global_load_lds(
        (const __attribute__((address_space(1))) unsigned int*)g,
        (__attribute__((address_space(3))) unsigned int*)lds, 16, 0, 0);
}

__device__ __forceinline__ unsigned short f2bu(float x) {
    __hip_bfloat16 h = __float2bfloat16(x);
    return *(unsigned short*)&h;
}

// ---------------------------------------------------------------------------
// hidden_states f32 -> bf16, 8 elems/thread
// ---------------------------------------------------------------------------
__global__ __launch_bounds__(256) void cvt_hs_kernel(
    const float* __restrict__ src, __hip_bfloat16* __restrict__ dst)
{
    size_t i = ((size_t)blockIdx.x * 256 + threadIdx.x) * 8;
    float4 a = *(const float4*)(src + i);
    float4 b = *(const float4*)(src + i + 4);
    unsigned short u[8] = { f2bu(a.x), f2bu(a.y), f2bu(a.z), f2bu(a.w),
                            f2bu(b.x), f2bu(b.y), f2bu(b.z), f2bu(b.w) };
    *(uint4*)(dst + i) = *(uint4*)u;
}

// ---------------------------------------------------------------------------
// Weight transpose + f32->bf16: W[K][N] f32 -> WT[N][K] bf16, 64x64 tiles.
// ---------------------------------------------------------------------------
__global__ __launch_bounds__(256) void transpose_w_kernel(
    const float* __restrict__ Wq, const float* __restrict__ Wk,
    const float* __restrict__ Wv, const float* __restrict__ Wo,
    __hip_bfloat16* __restrict__ WqkvT, __hip_bfloat16* __restrict__ WoT)
{
    __shared__ __attribute__((aligned(16))) unsigned short tile[64][72]; // 144B rows, 16B-aligned
    int id = blockIdx.x;
    const float* src; __hip_bfloat16* dst; int N, kt, nt;
    if (id < 1024)      { src = Wq; dst = WqkvT;                          N = 2048; kt = id >> 5;          nt = id & 31; }
    else if (id < 1536) { src = Wk; dst = WqkvT + (size_t)2048*2048;      N = 1024; kt = (id-1024) >> 4;   nt = (id-1024) & 15; }
    else if (id < 2048) { src = Wv; dst = WqkvT + (size_t)3072*2048;      N = 1024; kt = (id-1536) >> 4;   nt = (id-1536) & 15; }
    else                { src = Wo; dst = WoT;                            N = 2048; kt = (id-2048) >> 5;   nt = (id-2048) & 31; }
    int k0 = kt * 64, n0 = nt * 64;
    int tid = threadIdx.x;
#pragma unroll
    for (int p = 0; p < 2; ++p) {
        int c = p*256 + tid; int r = c >> 3, cc = (c & 7) * 8;
        const float* s = src + (size_t)(k0 + r)*N + n0 + cc;
        float4 a = *(const float4*)s;
        float4 b = *(const float4*)(s + 4);
        unsigned short u[8] = { f2bu(a.x), f2bu(a.y), f2bu(a.z), f2bu(a.w),
                                f2bu(b.x), f2bu(b.y), f2bu(b.z), f2bu(b.w) };
        *(uint4*)&tile[r][cc] = *(uint4*)u;
    }
    __syncthreads();
#pragma unroll
    for (int p = 0; p < 2; ++p) {
        int c = p*256 + tid; int r2 = c >> 3, c2 = (c & 7) * 8;
        uint4 o;
        o.x = tile[c2+0][r2] | ((unsigned)tile[c2+1][r2] << 16);
        o.y = tile[c2+2][r2] | ((unsigned)tile[c2+3][r2] << 16);
        o.z = tile[c2+4][r2] | ((unsigned)tile[c2+5][r2] << 16);
        o.w = tile[c2+6][r2] | ((unsigned)tile[c2+7][r2] << 16);
        *(uint4*)(dst + (size_t)(n0 + r2)*2048 + k0 + c2) = o;
    }
}

// ---------------------------------------------------------------------------
// V transpose: QKVraw[s][3072 + v] bf16 -> Vt[v][s] bf16
// ---------------------------------------------------------------------------
__global__ __launch_bounds__(256) void vtrans_kernel(
    const __hip_bfloat16* __restrict__ qkv, __hip_bfloat16* __restrict__ Vt)
{
    __shared__ __attribute__((aligned(16))) unsigned short tile[64][72];
    int s0 = blockIdx.x * 64;
    int v0 = blockIdx.y * 64;
    int tid = threadIdx.x;
#pragma unroll
    for (int p = 0; p < 2; ++p) {
        int c = p*256 + tid; int r = c >> 3, cc = (c & 7) * 8;
        uint4 v = *(const uint4*)(qkv + (size_t)(s0 + r)*4096 + 3072 + v0 + cc);
        *(uint4*)&tile[r][cc] = v;
    }
    __syncthreads();
#pragma unroll
    for (int p = 0; p < 2; ++p) {
        int c = p*256 + tid; int r2 = c >> 3, c2 = (c & 7) * 8;
        uint4 o;
        o.x = tile[c2+0][r2] | ((unsigned)tile[c2+1][r2] << 16);
        o.y = tile[c2+2][r2] | ((unsigned)tile[c2+3][r2] << 16);
        o.z = tile[c2+4][r2] | ((unsigned)tile[c2+5][r2] << 16);
        o.w = tile[c2+6][r2] | ((unsigned)tile[c2+7][r2] << 16);
        *(uint4*)(Vt + (size_t)(v0 + r2)*2048 + s0 + c2) = o;
    }
}

// ---------------------------------------------------------------------------
// GEMM: C[M][N] = A[M][K] * BT[N][K]^T.  128x128 tile, BK=32, 4 waves (2x2),
// global_load_lds staging, mfma_f32_16x16x32_bf16 (m97 structure).
// ---------------------------------------------------------------------------
template <typename OT>
__global__ __launch_bounds__(256) void gemm_bt_kernel(
    const __hip_bfloat16* __restrict__ A, const __hip_bfloat16* __restrict__ BT,
    OT* __restrict__ C, int M, int N, int K)
{
    __shared__ __attribute__((aligned(16))) __hip_bfloat16 As[128*32];
    __shared__ __attribute__((aligned(16))) __hip_bfloat16 Bs[128*32];
    const int tid  = threadIdx.x;
    const int lane = tid & 63;
    const int wave = tid >> 6;
    const int quad = lane >> 4, l15 = lane & 15;
    const int m0 = blockIdx.y * 128, n0 = blockIdx.x * 128;
    const int wm = (wave >> 1) * 64, wn = (wave & 1) * 64;

    f32x4 acc[4][4] = {};

    for (int k0 = 0; k0 < K; k0 += 32) {
#pragma unroll
        for (int p = 0; p < 2; ++p) {
            int c = p*256 + tid;
            int row = c >> 2, seg = c & 3;
            gld16((char*)As + c*16, A  + (size_t)(m0 + row)*K + k0 + seg*8);
            gld16((char*)Bs + c*16, BT + (size_t)(n0 + row)*K + k0 + seg*8);
        }
        __syncthreads();
        bf16x8 af[4], bfr[4];
#pragma unroll
        for (int t = 0; t < 4; ++t) {
            af[t]  = *(const bf16x8*)(As + (wm + t*16 + l15)*32 + quad*8);
            bfr[t] = *(const bf16x8*)(Bs + (wn + t*16 + l15)*32 + quad*8);
        }
#pragma unroll
        for (int mt = 0; mt < 4; ++mt)
#pragma unroll
            for (int nt = 0; nt < 4; ++nt)
                acc[mt][nt] = __builtin_amdgcn_mfma_f32_16x16x32_bf16(af[mt], bfr[nt], acc[mt][nt], 0, 0, 0);
        __syncthreads();
    }
#pragma unroll
    for (int mt = 0; mt < 4; ++mt)
#pragma unroll
        for (int nt = 0; nt < 4; ++nt)
#pragma unroll
            for (int r = 0; r < 4; ++r) {
                int row = m0 + wm + mt*16 + quad*4 + r;
                int col = n0 + wn + nt*16 + l15;
                if constexpr (__is_same(OT, float))
                    C[(size_t)row*N + col] = acc[mt][nt][r];
                else
                    C[(size_t)row*N + col] = __float2bfloat16(acc[mt][nt][r]);
            }
}

// ---------------------------------------------------------------------------
// RMSNorm + RoPE on Q and K rows of QKVraw. Block per s; wave per head-unit.
// Q output is pre-scaled by QK_SCALE*log2(e) (attention uses exp2 directly).
// ---------------------------------------------------------------------------
__global__ __launch_bounds__(256) void rmsrope_kernel(
    const __hip_bfloat16* __restrict__ qkv,
    const float* __restrict__ cosb, const float* __restrict__ sinb,
    const float* __restrict__ qsc,  const float* __restrict__ ksc,
    __hip_bfloat16* __restrict__ Qn, __hip_bfloat16* __restrict__ Kn)
{
    int s = blockIdx.x;
    int wave = threadIdx.x >> 6, lane = threadIdx.x & 63;
    float c1 = cosb[s*128 + lane];
    float c2 = cosb[s*128 + 64 + lane];
    float s1 = sinb[s*128 + lane];
    float s2 = sinb[s*128 + 64 + lane];
    for (int u = wave; u < 24; u += 4) {
        bool isq = (u < 16);
        int h = isq ? u : u - 16;
        const __hip_bfloat16* x = qkv + (size_t)s*4096 + (isq ? h*128 : 2048 + h*128);
        float x1 = (float)x[lane], x2 = (float)x[lane + 64];
        float ss = x1*x1 + x2*x2;
#pragma unroll
        for (int off = 32; off; off >>= 1) ss += __shfl_xor(ss, off);
        float r = rsqrtf(ss * (1.0f/128.0f) + RMS_EPS);
        if (isq) r *= QK_SCALE_L2E;        // fold attn scale + log2e into Q
        const float* sc = isq ? qsc : ksc;
        float y1 = x1 * r * sc[lane];
        float y2 = x2 * r * sc[lane + 64];
        float o1 = y1*c1 - y2*s1;   // d < 64:  x*c - x[d+64]*s
        float o2 = y2*c2 + y1*s2;   // d >= 64: x*c + x[d-64]*s
        __hip_bfloat16* dst = isq ? (Qn + (size_t)s*2048 + h*128)
                                  : (Kn + (size_t)s*1024 + h*128);
        dst[lane]      = __float2bfloat16(o1);
        dst[lane + 64] = __float2bfloat16(o2);
    }
}

// ---------------------------------------------------------------------------
// Flash attention, sliding-window causal — m97-style LDS staging (round 5).
//  * Block = 4 waves x 16 q-rows = 64 q-rows of one head; grid 512 (2 blk/CU).
//  * K-tile (64x128) and V-tile (128 d x 64 keys) staged into double-buffered
//    LDS via global_load_lds width=16: async DMA, no dest VGPRs -> all 8
//    staging instrs per thread in flight at once (fixes the round-3/4 MLP
//    failure where the register allocator serialized 32 register loads).
//  * One barrier per tile; next tile's staging issued right after it,
//    overlapping the whole tile's compute (double buffer).
//  * XOR-swizzled LDS layout (chunk c ^ (row&15) for K, c ^ (row&7) for V):
//    global_load_lds forbids padding (dest = base + lane*16), swizzle makes
//    ds_read_b128 fragment reads uniform across all 32 banks.
//  * No online max (scores bounded by RMS-norm: |s|<=~26 in log2 domain);
//    p=exp2(s), per-lane row-sums, single cross-lane reduce in epilogue.
// ---------------------------------------------------------------------------
__global__ __launch_bounds__(256, 2) void attn_kernel(
    const __hip_bfloat16* __restrict__ Qn,  // [S][2048], pre-scaled (log2 domain)
    const __hip_bfloat16* __restrict__ Kn,  // [S][1024]
    const __hip_bfloat16* __restrict__ Vt,  // [1024][S]
    __hip_bfloat16* __restrict__ O)         // [S][2048]
{
    __shared__ __attribute__((aligned(16))) __hip_bfloat16 Ksm[2][64*128];  // 2x16KB
    __shared__ __attribute__((aligned(16))) __hip_bfloat16 Vsm[2][128*64];  // 2x16KB
    __shared__ __attribute__((aligned(16))) __hip_bfloat16 P[4][16][76];

    const int bx   = blockIdx.x;
    const int h    = bx & 15;
    const int qb   = 31 - (bx >> 4);          // long-window blocks dispatched first
    const int i0   = qb * 64;
    const int hk   = h >> 1;
    const int tid  = threadIdx.x, wave = tid >> 6, lane = tid & 63;
    const int quad = lane >> 4, l15 = lane & 15;
    const int ib   = i0 + wave * 16;

    const __hip_bfloat16* Kh = Kn + hk * HDIM;              // row stride 1024
    const __hip_bfloat16* Vh = Vt + (size_t)(hk * HDIM) * 2048;

    // Q fragments (A-operand), fixed for the block
    bf16x8 qf[4];
    const __hip_bfloat16* qbase = Qn + (size_t)(ib + l15)*2048 + h*HDIM + quad*8;
#pragma unroll
    for (int kk = 0; kk < 4; ++kk) qf[kk] = *(const bf16x8*)(qbase + kk*32);

    f32x4 o[8] = {};
    float lrow[4] = {0.f, 0.f, 0.f, 0.f};

    int j_lo = i0 - WIN; if (j_lo < 0) j_lo = 0;
    const int jstart = j_lo & ~63;
    const int jend   = i0;                    // diagonal tile start

    // ---- cooperative staging of one (K,V) tile pair into buffer b ----
    auto stage = [&](int b, int j0) {
#pragma unroll
        for (int p = 0; p < 4; ++p) {         // K: 64 rows x 16 chunks of 16B
            int L = p*256 + tid;
            int r = L >> 4;
            int c = (L & 15) ^ (r & 15);      // XOR swizzle
            gld16((char*)&Ksm[b][0] + L*16, Kh + (size_t)(j0 + r)*1024 + c*8);
        }
#pragma unroll
        for (int p = 0; p < 4; ++p) {         // V: 128 d-rows x 8 chunks of 16B
            int L = p*256 + tid;
            int dv = L >> 3;
            int c = (L & 7) ^ (dv & 7);       // XOR swizzle
            gld16((char*)&Vsm[b][0] + L*16, Vh + (size_t)dv*2048 + j0 + c*8);
        }
    };

    stage(0, jstart);
    int cur = 0;
    for (int j0 = jstart; j0 <= jend; j0 += 64, cur ^= 1) {
        __syncthreads();                      // drains staging vmcnt + syncs buffers
        if (j0 + 64 <= jend) stage(cur ^ 1, j0 + 64);

        // ---- S = Q K^T (16 x 64 per wave), frags from swizzled LDS ----
        f32x4 sacc[4] = {};
#pragma unroll
        for (int nt = 0; nt < 4; ++nt) {
            const int r = nt*16 + l15;
#pragma unroll
            for (int kk = 0; kk < 4; ++kk) {
                const int cc = (kk*4 + quad) ^ l15;   // swizzled chunk
                bf16x8 kfr = *(const bf16x8*)(&Ksm[cur][0] + r*128 + cc*8);
                sacc[nt] = __builtin_amdgcn_mfma_f32_16x16x32_bf16(qf[kk], kfr, sacc[nt], 0, 0, 0);
            }
        }

        // ---- p = exp2(s), P write, per-lane row-sum ----
        const bool need_mask = (j0 + 63 > ib) || (j0 < ib + 15 - WIN);
        if (need_mask) {
#pragma unroll
            for (int nt = 0; nt < 4; ++nt) {
                int j = j0 + nt*16 + l15;
#pragma unroll
                for (int r = 0; r < 4; ++r) {
                    int i = ib + quad*4 + r;
                    bool valid = (j <= i) && (i - j <= WIN);
                    float p = valid ? __builtin_exp2f(sacc[nt][r]) : 0.f;
                    lrow[r] += p;
                    P[wave][quad*4 + r][nt*16 + l15] = __float2bfloat16(p);
                }
            }
        } else {
#pragma unroll
            for (int nt = 0; nt < 4; ++nt)
#pragma unroll
                for (int r = 0; r < 4; ++r) {
                    float p = __builtin_exp2f(sacc[nt][r]);
                    lrow[r] += p;
                    P[wave][quad*4 + r][nt*16 + l15] = __float2bfloat16(p);
                }
        }

        // ---- O += P V (P per-wave, lgkm-ordered; V frags from swizzled LDS) ----
#pragma unroll
        for (int ks = 0; ks < 2; ++ks) {
            bf16x8 pf = *(const bf16x8*)&P[wave][l15][ks*32 + quad*8];
#pragma unroll
            for (int dt = 0; dt < 8; ++dt) {
                const int dv = dt*16 + l15;
                const int cc = (ks*4 + quad) ^ (l15 & 7);
                bf16x8 vfr = *(const bf16x8*)(&Vsm[cur][0] + dv*64 + cc*8);
                o[dt] = __builtin_amdgcn_mfma_f32_16x16x32_bf16(pf, vfr, o[dt], 0, 0, 0);
            }
        }
    }

    // ---- epilogue: single cross-lane reduce of lrow, normalize, store ----
#pragma unroll
    for (int r = 0; r < 4; ++r) {
        lrow[r] += __shfl_xor(lrow[r], 1);
        lrow[r] += __shfl_xor(lrow[r], 2);
        lrow[r] += __shfl_xor(lrow[r], 4);
        lrow[r] += __shfl_xor(lrow[r], 8);
        float inv = 1.0f / lrow[r];
        int row = ib + quad*4 + r;
#pragma unroll
        for (int dt = 0; dt < 8; ++dt)
            O[(size_t)row*2048 + h*HDIM + dt*16 + l15] = __float2bfloat16(o[dt][r] * inv);
    }
}

// ---------------------------------------------------------------------------
extern "C" void kernel_launch(void* const* d_in, const int* in_sizes, int n_in,
                              void* d_out, int out_size, void* d_ws, size_t ws_size,
                              hipStream_t stream)
{
    (void)in_sizes; (void)n_in; (void)out_size; (void)ws_size;
    const float* hs   = (const float*)d_in[0];
    const float* cosb = (const float*)d_in[1];
    const float* sinb = (const float*)d_in[2];
    const float* Wq   = (const float*)d_in[3];
    const float* Wk   = (const float*)d_in[4];
    const float* Wv   = (const float*)d_in[5];
    const float* Wo   = (const float*)d_in[6];
    const float* qs   = (const float*)d_in[7];
    const float* ks   = (const float*)d_in[8];

    char* ws = (char*)d_ws;
    __hip_bfloat16* WqkvT = (__hip_bfloat16*)(ws);
    __hip_bfloat16* WoT   = (__hip_bfloat16*)(ws + (16u << 20));
    __hip_bfloat16* QKV   = (__hip_bfloat16*)(ws + (24u << 20));
    __hip_bfloat16* Qn    = (__hip_bfloat16*)(ws + (40u << 20));
    __hip_bfloat16* Kn    = (__hip_bfloat16*)(ws + (48u << 20));
    __hip_bfloat16* Vt    = (__hip_bfloat16*)(ws + (52u << 20));
    __hip_bfloat16* hsb   = (__hip_bfloat16*)(ws + (56u << 20)); // overlaid with AT
    __hip_bfloat16* AT    = (__hip_bfloat16*)(ws + (56u << 20)); // disjoint liveness

    cvt_hs_kernel<<<dim3(2048), dim3(256), 0, stream>>>(hs, hsb);
    transpose_w_kernel<<<dim3(3072), dim3(256), 0, stream>>>(Wq, Wk, Wv, Wo, WqkvT, WoT);
    gemm_bt_kernel<__hip_bfloat16><<<dim3(32, 16), dim3(256), 0, stream>>>(hsb, WqkvT, QKV, 2048, 4096, 2048);
    rmsrope_kernel<<<dim3(2048), dim3(256), 0, stream>>>(QKV, cosb, sinb, qs, ks, Qn, Kn);
    vtrans_kernel<<<dim3(32, 16), dim3(256), 0, stream>>>(QKV, Vt);
    attn_kernel<<<dim3(512), dim3(256), 0, stream>>>(Qn, Kn, Vt, AT);
    gemm_bt_kernel<float><<<dim3(16, 16), dim3(256), 0, stream>>>(AT, WoT, (float*)d_out, 2048, 2048, 2048);
}

// Round 6
// 254.056 us; speedup vs baseline: 1.4413x; 1.0296x over previous
//
#include <hip/hip_runtime.h>
#include <hip/hip_bf16.h>
#include <cmath>

// I/O: all inputs float32 (per reference setup_inputs), output float32.
// Internal compute: bf16 MFMA with fp32 accumulation.
//
// Workspace layout (64 MB total):
//  [0,16M)   WqkvT  [4096][2048] bf16   (rows: 0-2047 WqT, 2048-3071 WkT, 3072-4095 WvT)
//  [16,24M)  WoT    [2048][2048] bf16
//  [24,40M)  QKVraw [2048][4096] bf16
//  [40,48M)  Qn     [2048][2048] bf16   (post rms+rope, pre-scaled by QK_SCALE*log2e)
//  [48,52M)  Kn     [2048][1024] bf16
//  [52,56M)  Vt     [1024][2048] bf16   ([hkv*128 d][s])
//  [56,64M)  hsb    [2048][2048] bf16   (live: kernels 1-2)   }  overlaid,
//  [56,64M)  AT     [2048][2048] bf16   (live: kernels 4-5)   }  disjoint liveness

typedef __bf16 bf16x8 __attribute__((ext_vector_type(8)));
typedef float  f32x4  __attribute__((ext_vector_type(4)));

#define S_LEN    2048
#define NH       16
#define NKV      8
#define HDIM     128
#define WIN      1024
// QK_SCALE * log2(e): scores computed directly in log2 domain -> exp2
#define QK_SCALE_L2E 0.12751744595f
#define RMS_EPS  1e-6f

__device__ __forceinline__ void gld16(void* lds, const void* g) {
    __builtin_amdgcn_global_load_lds(
        (const __attribute__((address_space(1))) unsigned int*)g,
        (__attribute__((address_space(3))) unsigned int*)lds, 16, 0, 0);
}

__device__ __forceinline__ unsigned short f2bu(float x) {
    __hip_bfloat16 h = __float2bfloat16(x);
    return *(unsigned short*)&h;
}

// ---------------------------------------------------------------------------
// Fused: weight transpose + f32->bf16 (blocks 0..3071)  AND
//        hidden_states f32->bf16 convert (blocks 3072..5119).
// ---------------------------------------------------------------------------
__global__ __launch_bounds__(256) void trans_cvt_kernel(
    const float* __restrict__ Wq, const float* __restrict__ Wk,
    const float* __restrict__ Wv, const float* __restrict__ Wo,
    const float* __restrict__ hs,
    __hip_bfloat16* __restrict__ WqkvT, __hip_bfloat16* __restrict__ WoT,
    __hip_bfloat16* __restrict__ hsb)
{
    __shared__ __attribute__((aligned(16))) unsigned short tile[64][72]; // 144B rows
    int id = blockIdx.x;
    if (id >= 3072) {   // ---- hidden_states convert: 8 elems/thread ----
        size_t i = ((size_t)(id - 3072) * 256 + threadIdx.x) * 8;
        float4 a = *(const float4*)(hs + i);
        float4 b = *(const float4*)(hs + i + 4);
        unsigned short u[8] = { f2bu(a.x), f2bu(a.y), f2bu(a.z), f2bu(a.w),
                                f2bu(b.x), f2bu(b.y), f2bu(b.z), f2bu(b.w) };
        *(uint4*)(hsb + i) = *(uint4*)u;
        return;
    }
    const float* src; __hip_bfloat16* dst; int N, kt, nt;
    if (id < 1024)      { src = Wq; dst = WqkvT;                          N = 2048; kt = id >> 5;          nt = id & 31; }
    else if (id < 1536) { src = Wk; dst = WqkvT + (size_t)2048*2048;      N = 1024; kt = (id-1024) >> 4;   nt = (id-1024) & 15; }
    else if (id < 2048) { src = Wv; dst = WqkvT + (size_t)3072*2048;      N = 1024; kt = (id-1536) >> 4;   nt = (id-1536) & 15; }
    else                { src = Wo; dst = WoT;                            N = 2048; kt = (id-2048) >> 5;   nt = (id-2048) & 31; }
    int k0 = kt * 64, n0 = nt * 64;
    int tid = threadIdx.x;
#pragma unroll
    for (int p = 0; p < 2; ++p) {
        int c = p*256 + tid; int r = c >> 3, cc = (c & 7) * 8;
        const float* s = src + (size_t)(k0 + r)*N + n0 + cc;
        float4 a = *(const float4*)s;
        float4 b = *(const float4*)(s + 4);
        unsigned short u[8] = { f2bu(a.x), f2bu(a.y), f2bu(a.z), f2bu(a.w),
                                f2bu(b.x), f2bu(b.y), f2bu(b.z), f2bu(b.w) };
        *(uint4*)&tile[r][cc] = *(uint4*)u;
    }
    __syncthreads();
#pragma unroll
    for (int p = 0; p < 2; ++p) {
        int c = p*256 + tid; int r2 = c >> 3, c2 = (c & 7) * 8;
        uint4 o;
        o.x = tile[c2+0][r2] | ((unsigned)tile[c2+1][r2] << 16);
        o.y = tile[c2+2][r2] | ((unsigned)tile[c2+3][r2] << 16);
        o.z = tile[c2+4][r2] | ((unsigned)tile[c2+5][r2] << 16);
        o.w = tile[c2+6][r2] | ((unsigned)tile[c2+7][r2] << 16);
        *(uint4*)(dst + (size_t)(n0 + r2)*2048 + k0 + c2) = o;
    }
}

// ---------------------------------------------------------------------------
// GEMM: C[M][N] = A[M][K] * BT[N][K]^T.  128x128 tile, BK=32, 4 waves (2x2),
// global_load_lds staging, mfma_f32_16x16x32_bf16 (m97 structure).
// Round-6: XOR-swizzled LDS layout — chunk c of row r stored at slot
// c ^ ((r>>1)&3). Kills the 8-way ds_read_b128 bank conflict (4.19M conflict
// cycles/dispatch in round 5): quad's 16 lanes now cover 8 bank-groups x2
// (2 lanes/bank = free per m136). Fragment-read slot is lane-constant:
// sw = quad ^ ((l15>>1)&3), zero extra VALU in the K-loop.
// ---------------------------------------------------------------------------
template <typename OT>
__global__ __launch_bounds__(256) void gemm_bt_kernel(
    const __hip_bfloat16* __restrict__ A, const __hip_bfloat16* __restrict__ BT,
    OT* __restrict__ C, int M, int N, int K)
{
    __shared__ __attribute__((aligned(16))) __hip_bfloat16 As[128*32];
    __shared__ __attribute__((aligned(16))) __hip_bfloat16 Bs[128*32];
    const int tid  = threadIdx.x;
    const int lane = tid & 63;
    const int wave = tid >> 6;
    const int quad = lane >> 4, l15 = lane & 15;
    const int m0 = blockIdx.y * 128, n0 = blockIdx.x * 128;
    const int wm = (wave >> 1) * 64, wn = (wave & 1) * 64;
    const int sw = (quad ^ ((l15 >> 1) & 3)) * 8;   // swizzled chunk offset (bf16 units)

    f32x4 acc[4][4] = {};

    for (int k0 = 0; k0 < K; k0 += 32) {
#pragma unroll
        for (int p = 0; p < 2; ++p) {
            int c = p*256 + tid;
            int row = c >> 2, seg = c & 3;
            int cs = seg ^ ((row >> 1) & 3);        // source chunk for this LDS slot
            gld16((char*)As + c*16, A  + (size_t)(m0 + row)*K + k0 + cs*8);
            gld16((char*)Bs + c*16, BT + (size_t)(n0 + row)*K + k0 + cs*8);
        }
        __syncthreads();
        bf16x8 af[4], bfr[4];
#pragma unroll
        for (int t = 0; t < 4; ++t) {
            af[t]  = *(const bf16x8*)(As + (wm + t*16 + l15)*32 + sw);
            bfr[t] = *(const bf16x8*)(Bs + (wn + t*16 + l15)*32 + sw);
        }
#pragma unroll
        for (int mt = 0; mt < 4; ++mt)
#pragma unroll
            for (int nt = 0; nt < 4; ++nt)
                acc[mt][nt] = __builtin_amdgcn_mfma_f32_16x16x32_bf16(af[mt], bfr[nt], acc[mt][nt], 0, 0, 0);
        __syncthreads();
    }
#pragma unroll
    for (int mt = 0; mt < 4; ++mt)
#pragma unroll
        for (int nt = 0; nt < 4; ++nt)
#pragma unroll
            for (int r = 0; r < 4; ++r) {
                int row = m0 + wm + mt*16 + quad*4 + r;
                int col = n0 + wn + nt*16 + l15;
                if constexpr (__is_same(OT, float))
                    C[(size_t)row*N + col] = acc[mt][nt][r];
                else
                    C[(size_t)row*N + col] = __float2bfloat16(acc[mt][nt][r]);
            }
}

// ---------------------------------------------------------------------------
// Fused: RMSNorm+RoPE on Q,K rows of QKVraw (blocks 0..2047, one s each)
//        AND V transpose QKVraw -> Vt (blocks 2048..2559, 64x64 tiles).
// Q output pre-scaled by QK_SCALE*log2(e) (attention uses exp2 directly).
// ---------------------------------------------------------------------------
__global__ __launch_bounds__(256) void rms_vt_kernel(
    const __hip_bfloat16* __restrict__ qkv,
    const float* __restrict__ cosb, const float* __restrict__ sinb,
    const float* __restrict__ qsc,  const float* __restrict__ ksc,
    __hip_bfloat16* __restrict__ Qn, __hip_bfloat16* __restrict__ Kn,
    __hip_bfloat16* __restrict__ Vt)
{
    __shared__ __attribute__((aligned(16))) unsigned short tile[64][72];
    int id = blockIdx.x;
    if (id >= 2048) {   // ---- V transpose tile ----
        int t  = id - 2048;                 // 512 tiles: 32 (s) x 16 (v)
        int s0 = (t & 31) * 64;
        int v0 = (t >> 5) * 64;
        int tid = threadIdx.x;
#pragma unroll
        for (int p = 0; p < 2; ++p) {
            int c = p*256 + tid; int r = c >> 3, cc = (c & 7) * 8;
            uint4 v = *(const uint4*)(qkv + (size_t)(s0 + r)*4096 + 3072 + v0 + cc);
            *(uint4*)&tile[r][cc] = v;
        }
        __syncthreads();
#pragma unroll
        for (int p = 0; p < 2; ++p) {
            int c = p*256 + tid; int r2 = c >> 3, c2 = (c & 7) * 8;
            uint4 o;
            o.x = tile[c2+0][r2] | ((unsigned)tile[c2+1][r2] << 16);
            o.y = tile[c2+2][r2] | ((unsigned)tile[c2+3][r2] << 16);
            o.z = tile[c2+4][r2] | ((unsigned)tile[c2+5][r2] << 16);
            o.w = tile[c2+6][r2] | ((unsigned)tile[c2+7][r2] << 16);
            *(uint4*)(Vt + (size_t)(v0 + r2)*2048 + s0 + c2) = o;
        }
        return;
    }
    // ---- RMSNorm + RoPE ----
    int s = id;
    int wave = threadIdx.x >> 6, lane = threadIdx.x & 63;
    float c1 = cosb[s*128 + lane];
    float c2 = cosb[s*128 + 64 + lane];
    float s1 = sinb[s*128 + lane];
    float s2 = sinb[s*128 + 64 + lane];
    for (int u = wave; u < 24; u += 4) {
        bool isq = (u < 16);
        int h = isq ? u : u - 16;
        const __hip_bfloat16* x = qkv + (size_t)s*4096 + (isq ? h*128 : 2048 + h*128);
        float x1 = (float)x[lane], x2 = (float)x[lane + 64];
        float ss = x1*x1 + x2*x2;
#pragma unroll
        for (int off = 32; off; off >>= 1) ss += __shfl_xor(ss, off);
        float r = rsqrtf(ss * (1.0f/128.0f) + RMS_EPS);
        if (isq) r *= QK_SCALE_L2E;        // fold attn scale + log2e into Q
        const float* sc = isq ? qsc : ksc;
        float y1 = x1 * r * sc[lane];
        float y2 = x2 * r * sc[lane + 64];
        float o1 = y1*c1 - y2*s1;   // d < 64:  x*c - x[d+64]*s
        float o2 = y2*c2 + y1*s2;   // d >= 64: x*c + x[d-64]*s
        __hip_bfloat16* dst = isq ? (Qn + (size_t)s*2048 + h*128)
                                  : (Kn + (size_t)s*1024 + h*128);
        dst[lane]      = __float2bfloat16(o1);
        dst[lane + 64] = __float2bfloat16(o2);
    }
}

// ---------------------------------------------------------------------------
// Flash attention, sliding-window causal — m97-style LDS staging.
//  * Block = 4 waves x 16 q-rows = 64 q-rows of one head; grid 512 (2 blk/CU).
//  * K/V tiles staged into double-buffered LDS via global_load_lds width=16.
//  * XOR-swizzled LDS layouts; one barrier per tile; next staging issued
//    right after it (double buffer overlaps full tile compute).
//  * No online max (scores bounded by RMS-norm); p=exp2(s), per-lane row
//    sums, single cross-lane reduce in epilogue.
// ---------------------------------------------------------------------------
__global__ __launch_bounds__(256, 2) void attn_kernel(
    const __hip_bfloat16* __restrict__ Qn,  // [S][2048], pre-scaled (log2 domain)
    const __hip_bfloat16* __restrict__ Kn,  // [S][1024]
    const __hip_bfloat16* __restrict__ Vt,  // [1024][S]
    __hip_bfloat16* __restrict__ O)         // [S][2048]
{
    __shared__ __attribute__((aligned(16))) __hip_bfloat16 Ksm[2][64*128];  // 2x16KB
    __shared__ __attribute__((aligned(16))) __hip_bfloat16 Vsm[2][128*64];  // 2x16KB
    __shared__ __attribute__((aligned(16))) __hip_bfloat16 P[4][16][76];

    const int bx   = blockIdx.x;
    const int h    = bx & 15;
    const int qb   = 31 - (bx >> 4);          // long-window blocks dispatched first
    const int i0   = qb * 64;
    const int hk   = h >> 1;
    const int tid  = threadIdx.x, wave = tid >> 6, lane = tid & 63;
    const int quad = lane >> 4, l15 = lane & 15;
    const int ib   = i0 + wave * 16;

    const __hip_bfloat16* Kh = Kn + hk * HDIM;              // row stride 1024
    const __hip_bfloat16* Vh = Vt + (size_t)(hk * HDIM) * 2048;

    // Q fragments (A-operand), fixed for the block
    bf16x8 qf[4];
    const __hip_bfloat16* qbase = Qn + (size_t)(ib + l15)*2048 + h*HDIM + quad*8;
#pragma unroll
    for (int kk = 0; kk < 4; ++kk) qf[kk] = *(const bf16x8*)(qbase + kk*32);

    f32x4 o[8] = {};
    float lrow[4] = {0.f, 0.f, 0.f, 0.f};

    int j_lo = i0 - WIN; if (j_lo < 0) j_lo = 0;
    const int jstart = j_lo & ~63;
    const int jend   = i0;                    // diagonal tile start

    // ---- cooperative staging of one (K,V) tile pair into buffer b ----
    auto stage = [&](int b, int j0) {
#pragma unroll
        for (int p = 0; p < 4; ++p) {         // K: 64 rows x 16 chunks of 16B
            int L = p*256 + tid;
            int r = L >> 4;
            int c = (L & 15) ^ (r & 15);      // XOR swizzle
            gld16((char*)&Ksm[b][0] + L*16, Kh + (size_t)(j0 + r)*1024 + c*8);
        }
#pragma unroll
        for (int p = 0; p < 4; ++p) {         // V: 128 d-rows x 8 chunks of 16B
            int L = p*256 + tid;
            int dv = L >> 3;
            int c = (L & 7) ^ (dv & 7);       // XOR swizzle
            gld16((char*)&Vsm[b][0] + L*16, Vh + (size_t)dv*2048 + j0 + c*8);
        }
    };

    stage(0, jstart);
    int cur = 0;
    for (int j0 = jstart; j0 <= jend; j0 += 64, cur ^= 1) {
        __syncthreads();                      // drains staging vmcnt + syncs buffers
        if (j0 + 64 <= jend) stage(cur ^ 1, j0 + 64);

        // ---- S = Q K^T (16 x 64 per wave), frags from swizzled LDS ----
        f32x4 sacc[4] = {};
#pragma unroll
        for (int nt = 0; nt < 4; ++nt) {
            const int r = nt*16 + l15;
#pragma unroll
            for (int kk = 0; kk < 4; ++kk) {
                const int cc = (kk*4 + quad) ^ l15;   // swizzled chunk
                bf16x8 kfr = *(const bf16x8*)(&Ksm[cur][0] + r*128 + cc*8);
                sacc[nt] = __builtin_amdgcn_mfma_f32_16x16x32_bf16(qf[kk], kfr, sacc[nt], 0, 0, 0);
            }
        }

        // ---- p = exp2(s), P write, per-lane row-sum ----
        const bool need_mask = (j0 + 63 > ib) || (j0 < ib + 15 - WIN);
        if (need_mask) {
#pragma unroll
            for (int nt = 0; nt < 4; ++nt) {
                int j = j0 + nt*16 + l15;
#pragma unroll
                for (int r = 0; r < 4; ++r) {
                    int i = ib + quad*4 + r;
                    bool valid = (j <= i) && (i - j <= WIN);
                    float p = valid ? __builtin_exp2f(sacc[nt][r]) : 0.f;
                    lrow[r] += p;
                    P[wave][quad*4 + r][nt*16 + l15] = __float2bfloat16(p);
                }
            }
        } else {
#pragma unroll
            for (int nt = 0; nt < 4; ++nt)
#pragma unroll
                for (int r = 0; r < 4; ++r) {
                    float p = __builtin_exp2f(sacc[nt][r]);
                    lrow[r] += p;
                    P[wave][quad*4 + r][nt*16 + l15] = __float2bfloat16(p);
                }
        }

        // ---- O += P V (P per-wave, lgkm-ordered; V frags from swizzled LDS) ----
#pragma unroll
        for (int ks = 0; ks < 2; ++ks) {
            bf16x8 pf = *(const bf16x8*)&P[wave][l15][ks*32 + quad*8];
#pragma unroll
            for (int dt = 0; dt < 8; ++dt) {
                const int dv = dt*16 + l15;
                const int cc = (ks*4 + quad) ^ (l15 & 7);
                bf16x8 vfr = *(const bf16x8*)(&Vsm[cur][0] + dv*64 + cc*8);
                o[dt] = __builtin_amdgcn_mfma_f32_16x16x32_bf16(pf, vfr, o[dt], 0, 0, 0);
            }
        }
    }

    // ---- epilogue: single cross-lane reduce of lrow, normalize, store ----
#pragma unroll
    for (int r = 0; r < 4; ++r) {
        lrow[r] += __shfl_xor(lrow[r], 1);
        lrow[r] += __shfl_xor(lrow[r], 2);
        lrow[r] += __shfl_xor(lrow[r], 4);
        lrow[r] += __shfl_xor(lrow[r], 8);
        float inv = 1.0f / lrow[r];
        int row = ib + quad*4 + r;
#pragma unroll
        for (int dt = 0; dt < 8; ++dt)
            O[(size_t)row*2048 + h*HDIM + dt*16 + l15] = __float2bfloat16(o[dt][r] * inv);
    }
}

// ---------------------------------------------------------------------------
extern "C" void kernel_launch(void* const* d_in, const int* in_sizes, int n_in,
                              void* d_out, int out_size, void* d_ws, size_t ws_size,
                              hipStream_t stream)
{
    (void)in_sizes; (void)n_in; (void)out_size; (void)ws_size;
    const float* hs   = (const float*)d_in[0];
    const float* cosb = (const float*)d_in[1];
    const float* sinb = (const float*)d_in[2];
    const float* Wq   = (const float*)d_in[3];
    const float* Wk   = (const float*)d_in[4];
    const float* Wv   = (const float*)d_in[5];
    const float* Wo   = (const float*)d_in[6];
    const float* qs   = (const float*)d_in[7];
    const float* ks   = (const float*)d_in[8];

    char* ws = (char*)d_ws;
    __hip_bfloat16* WqkvT = (__hip_bfloat16*)(ws);
    __hip_bfloat16* WoT   = (__hip_bfloat16*)(ws + (16u << 20));
    __hip_bfloat16* QKV   = (__hip_bfloat16*)(ws + (24u << 20));
    __hip_bfloat16* Qn    = (__hip_bfloat16*)(ws + (40u << 20));
    __hip_bfloat16* Kn    = (__hip_bfloat16*)(ws + (48u << 20));
    __hip_bfloat16* Vt    = (__hip_bfloat16*)(ws + (52u << 20));
    __hip_bfloat16* hsb   = (__hip_bfloat16*)(ws + (56u << 20)); // overlaid with AT
    __hip_bfloat16* AT    = (__hip_bfloat16*)(ws + (56u << 20)); // disjoint liveness

    trans_cvt_kernel<<<dim3(5120), dim3(256), 0, stream>>>(Wq, Wk, Wv, Wo, hs, WqkvT, WoT, hsb);
    gemm_bt_kernel<__hip_bfloat16><<<dim3(32, 16), dim3(256), 0, stream>>>(hsb, WqkvT, QKV, 2048, 4096, 2048);
    rms_vt_kernel<<<dim3(2560), dim3(256), 0, stream>>>(QKV, cosb, sinb, qs, ks, Qn, Kn, Vt);
    attn_kernel<<<dim3(512), dim3(256), 0, stream>>>(Qn, Kn, Vt, AT);
    gemm_bt_kernel<float><<<dim3(16, 16), dim3(256), 0, stream>>>(AT, WoT, (float*)d_out, 2048, 2048, 2048);
}

// Round 7
// 251.228 us; speedup vs baseline: 1.4575x; 1.0113x over previous
//
#include <hip/hip_runtime.h>
#include <hip/hip_bf16.h>
#include <cmath>

// I/O: all inputs float32 (per reference setup_inputs), output float32.
// Internal compute: bf16 MFMA with fp32 accumulation.
//
// Workspace layout (64 MB total):
//  [0,16M)   WqkvT  [4096][2048] bf16   (rows: 0-2047 WqT, 2048-3071 WkT, 3072-4095 WvT)
//  [16,24M)  WoT    [2048][2048] bf16
//  [24,40M)  QKVraw [2048][4096] bf16
//  [40,48M)  Qn     [2048][2048] bf16   (post rms+rope, pre-scaled by QK_SCALE*log2e)
//  [48,52M)  Kn     [2048][1024] bf16
//  [52,56M)  Vt     [1024][2048] bf16   ([hkv*128 d][s])
//  [56,64M)  hsb    [2048][2048] bf16   (live: kernels 1-2)   }  overlaid,
//  [56,64M)  AT     [2048][2048] bf16   (live: kernels 4-5)   }  disjoint liveness

typedef __bf16 bf16x8 __attribute__((ext_vector_type(8)));
typedef float  f32x4  __attribute__((ext_vector_type(4)));

#define S_LEN    2048
#define NH       16
#define NKV      8
#define HDIM     128
#define WIN      1024
// QK_SCALE * log2(e): scores computed directly in log2 domain -> exp2
#define QK_SCALE_L2E 0.12751744595f
#define RMS_EPS  1e-6f

__device__ __forceinline__ void gld16(void* lds, const void* g) {
    __builtin_amdgcn_global_load_lds(
        (const __attribute__((address_space(1))) unsigned int*)g,
        (__attribute__((address_space(3))) unsigned int*)lds, 16, 0, 0);
}

__device__ __forceinline__ unsigned short f2bu(float x) {
    __hip_bfloat16 h = __float2bfloat16(x);
    return *(unsigned short*)&h;
}

// ---------------------------------------------------------------------------
// Fused: weight transpose + f32->bf16 (blocks 0..3071)  AND
//        hidden_states f32->bf16 convert (blocks 3072..5119).
// ---------------------------------------------------------------------------
__global__ __launch_bounds__(256) void trans_cvt_kernel(
    const float* __restrict__ Wq, const float* __restrict__ Wk,
    const float* __restrict__ Wv, const float* __restrict__ Wo,
    const float* __restrict__ hs,
    __hip_bfloat16* __restrict__ WqkvT, __hip_bfloat16* __restrict__ WoT,
    __hip_bfloat16* __restrict__ hsb)
{
    __shared__ __attribute__((aligned(16))) unsigned short tile[64][72]; // 144B rows
    int id = blockIdx.x;
    if (id >= 3072) {   // ---- hidden_states convert: 8 elems/thread ----
        size_t i = ((size_t)(id - 3072) * 256 + threadIdx.x) * 8;
        float4 a = *(const float4*)(hs + i);
        float4 b = *(const float4*)(hs + i + 4);
        unsigned short u[8] = { f2bu(a.x), f2bu(a.y), f2bu(a.z), f2bu(a.w),
                                f2bu(b.x), f2bu(b.y), f2bu(b.z), f2bu(b.w) };
        *(uint4*)(hsb + i) = *(uint4*)u;
        return;
    }
    const float* src; __hip_bfloat16* dst; int N, kt, nt;
    if (id < 1024)      { src = Wq; dst = WqkvT;                          N = 2048; kt = id >> 5;          nt = id & 31; }
    else if (id < 1536) { src = Wk; dst = WqkvT + (size_t)2048*2048;      N = 1024; kt = (id-1024) >> 4;   nt = (id-1024) & 15; }
    else if (id < 2048) { src = Wv; dst = WqkvT + (size_t)3072*2048;      N = 1024; kt = (id-1536) >> 4;   nt = (id-1536) & 15; }
    else                { src = Wo; dst = WoT;                            N = 2048; kt = (id-2048) >> 5;   nt = (id-2048) & 31; }
    int k0 = kt * 64, n0 = nt * 64;
    int tid = threadIdx.x;
#pragma unroll
    for (int p = 0; p < 2; ++p) {
        int c = p*256 + tid; int r = c >> 3, cc = (c & 7) * 8;
        const float* s = src + (size_t)(k0 + r)*N + n0 + cc;
        float4 a = *(const float4*)s;
        float4 b = *(const float4*)(s + 4);
        unsigned short u[8] = { f2bu(a.x), f2bu(a.y), f2bu(a.z), f2bu(a.w),
                                f2bu(b.x), f2bu(b.y), f2bu(b.z), f2bu(b.w) };
        *(uint4*)&tile[r][cc] = *(uint4*)u;
    }
    __syncthreads();
#pragma unroll
    for (int p = 0; p < 2; ++p) {
        int c = p*256 + tid; int r2 = c >> 3, c2 = (c & 7) * 8;
        uint4 o;
        o.x = tile[c2+0][r2] | ((unsigned)tile[c2+1][r2] << 16);
        o.y = tile[c2+2][r2] | ((unsigned)tile[c2+3][r2] << 16);
        o.z = tile[c2+4][r2] | ((unsigned)tile[c2+5][r2] << 16);
        o.w = tile[c2+6][r2] | ((unsigned)tile[c2+7][r2] << 16);
        *(uint4*)(dst + (size_t)(n0 + r2)*2048 + k0 + c2) = o;
    }
}

// ---------------------------------------------------------------------------
// GEMM: C[M][N] = A[M][K] * BT[N][K]^T.
// Round-7: BM=128 x BN=64 tile, BK=32, 256 thr (4 waves, 2x2, wave-tile
// 64x32). Halving BN doubles the grid -> more co-resident blocks per CU
// (the round-5/6 data shows TF scales ~linearly with barrier streams/CU:
// 1->292, 2->583, 4->~874 TF). XOR-swizzled LDS (conflict-free, round 6).
// ---------------------------------------------------------------------------
template <typename OT>
__global__ __launch_bounds__(256) void gemm_bt_kernel(
    const __hip_bfloat16* __restrict__ A, const __hip_bfloat16* __restrict__ BT,
    OT* __restrict__ C, int M, int N, int K)
{
    __shared__ __attribute__((aligned(16))) __hip_bfloat16 As[128*32];
    __shared__ __attribute__((aligned(16))) __hip_bfloat16 Bs[64*32];
    const int tid  = threadIdx.x;
    const int lane = tid & 63;
    const int wave = tid >> 6;
    const int quad = lane >> 4, l15 = lane & 15;
    const int m0 = blockIdx.y * 128, n0 = blockIdx.x * 64;
    const int wm = (wave >> 1) * 64, wn = (wave & 1) * 32;
    const int sw = (quad ^ ((l15 >> 1) & 3)) * 8;   // swizzled chunk offset (bf16 units)

    f32x4 acc[4][2] = {};

    for (int k0 = 0; k0 < K; k0 += 32) {
#pragma unroll
        for (int p = 0; p < 2; ++p) {                 // A: 128 rows x 4 chunks
            int c = p*256 + tid;
            int row = c >> 2, seg = c & 3;
            int cs = seg ^ ((row >> 1) & 3);
            gld16((char*)As + c*16, A + (size_t)(m0 + row)*K + k0 + cs*8);
        }
        {                                             // B: 64 rows x 4 chunks
            int c = tid;
            int row = c >> 2, seg = c & 3;
            int cs = seg ^ ((row >> 1) & 3);
            gld16((char*)Bs + c*16, BT + (size_t)(n0 + row)*K + k0 + cs*8);
        }
        __syncthreads();
        bf16x8 af[4], bfr[2];
#pragma unroll
        for (int t = 0; t < 4; ++t)
            af[t]  = *(const bf16x8*)(As + (wm + t*16 + l15)*32 + sw);
#pragma unroll
        for (int t = 0; t < 2; ++t)
            bfr[t] = *(const bf16x8*)(Bs + (wn + t*16 + l15)*32 + sw);
#pragma unroll
        for (int mt = 0; mt < 4; ++mt)
#pragma unroll
            for (int nt = 0; nt < 2; ++nt)
                acc[mt][nt] = __builtin_amdgcn_mfma_f32_16x16x32_bf16(af[mt], bfr[nt], acc[mt][nt], 0, 0, 0);
        __syncthreads();
    }
#pragma unroll
    for (int mt = 0; mt < 4; ++mt)
#pragma unroll
        for (int nt = 0; nt < 2; ++nt)
#pragma unroll
            for (int r = 0; r < 4; ++r) {
                int row = m0 + wm + mt*16 + quad*4 + r;
                int col = n0 + wn + nt*16 + l15;
                if constexpr (__is_same(OT, float))
                    C[(size_t)row*N + col] = acc[mt][nt][r];
                else
                    C[(size_t)row*N + col] = __float2bfloat16(acc[mt][nt][r]);
            }
}

// ---------------------------------------------------------------------------
// Fused: RMSNorm+RoPE on Q,K rows of QKVraw (blocks 0..2047, one s each)
//        AND V transpose QKVraw -> Vt (blocks 2048..2559, 64x64 tiles).
// Q output pre-scaled by QK_SCALE*log2(e) (attention uses exp2 directly).
// ---------------------------------------------------------------------------
__global__ __launch_bounds__(256) void rms_vt_kernel(
    const __hip_bfloat16* __restrict__ qkv,
    const float* __restrict__ cosb, const float* __restrict__ sinb,
    const float* __restrict__ qsc,  const float* __restrict__ ksc,
    __hip_bfloat16* __restrict__ Qn, __hip_bfloat16* __restrict__ Kn,
    __hip_bfloat16* __restrict__ Vt)
{
    __shared__ __attribute__((aligned(16))) unsigned short tile[64][72];
    int id = blockIdx.x;
    if (id >= 2048) {   // ---- V transpose tile ----
        int t  = id - 2048;                 // 512 tiles: 32 (s) x 16 (v)
        int s0 = (t & 31) * 64;
        int v0 = (t >> 5) * 64;
        int tid = threadIdx.x;
#pragma unroll
        for (int p = 0; p < 2; ++p) {
            int c = p*256 + tid; int r = c >> 3, cc = (c & 7) * 8;
            uint4 v = *(const uint4*)(qkv + (size_t)(s0 + r)*4096 + 3072 + v0 + cc);
            *(uint4*)&tile[r][cc] = v;
        }
        __syncthreads();
#pragma unroll
        for (int p = 0; p < 2; ++p) {
            int c = p*256 + tid; int r2 = c >> 3, c2 = (c & 7) * 8;
            uint4 o;
            o.x = tile[c2+0][r2] | ((unsigned)tile[c2+1][r2] << 16);
            o.y = tile[c2+2][r2] | ((unsigned)tile[c2+3][r2] << 16);
            o.z = tile[c2+4][r2] | ((unsigned)tile[c2+5][r2] << 16);
            o.w = tile[c2+6][r2] | ((unsigned)tile[c2+7][r2] << 16);
            *(uint4*)(Vt + (size_t)(v0 + r2)*2048 + s0 + c2) = o;
        }
        return;
    }
    // ---- RMSNorm + RoPE ----
    int s = id;
    int wave = threadIdx.x >> 6, lane = threadIdx.x & 63;
    float c1 = cosb[s*128 + lane];
    float c2 = cosb[s*128 + 64 + lane];
    float s1 = sinb[s*128 + lane];
    float s2 = sinb[s*128 + 64 + lane];
    for (int u = wave; u < 24; u += 4) {
        bool isq = (u < 16);
        int h = isq ? u : u - 16;
        const __hip_bfloat16* x = qkv + (size_t)s*4096 + (isq ? h*128 : 2048 + h*128);
        float x1 = (float)x[lane], x2 = (float)x[lane + 64];
        float ss = x1*x1 + x2*x2;
#pragma unroll
        for (int off = 32; off; off >>= 1) ss += __shfl_xor(ss, off);
        float r = rsqrtf(ss * (1.0f/128.0f) + RMS_EPS);
        if (isq) r *= QK_SCALE_L2E;        // fold attn scale + log2e into Q
        const float* sc = isq ? qsc : ksc;
        float y1 = x1 * r * sc[lane];
        float y2 = x2 * r * sc[lane + 64];
        float o1 = y1*c1 - y2*s1;   // d < 64:  x*c - x[d+64]*s
        float o2 = y2*c2 + y1*s2;   // d >= 64: x*c + x[d-64]*s
        __hip_bfloat16* dst = isq ? (Qn + (size_t)s*2048 + h*128)
                                  : (Kn + (size_t)s*1024 + h*128);
        dst[lane]      = __float2bfloat16(o1);
        dst[lane + 64] = __float2bfloat16(o2);
    }
}

// ---------------------------------------------------------------------------
// Flash attention, sliding-window causal — m97-style LDS staging.
//  * Block = 4 waves x 16 q-rows = 64 q-rows of one head; grid 512 (2 blk/CU).
//  * K/V tiles staged into double-buffered LDS via global_load_lds width=16.
//  * XOR-swizzled LDS layouts; one barrier per tile; next staging issued
//    right after it (double buffer overlaps full tile compute).
//  * No online max (scores bounded by RMS-norm); p=exp2(s), per-lane row
//    sums, single cross-lane reduce in epilogue.
// ---------------------------------------------------------------------------
__global__ __launch_bounds__(256, 2) void attn_kernel(
    const __hip_bfloat16* __restrict__ Qn,  // [S][2048], pre-scaled (log2 domain)
    const __hip_bfloat16* __restrict__ Kn,  // [S][1024]
    const __hip_bfloat16* __restrict__ Vt,  // [1024][S]
    __hip_bfloat16* __restrict__ O)         // [S][2048]
{
    __shared__ __attribute__((aligned(16))) __hip_bfloat16 Ksm[2][64*128];  // 2x16KB
    __shared__ __attribute__((aligned(16))) __hip_bfloat16 Vsm[2][128*64];  // 2x16KB
    __shared__ __attribute__((aligned(16))) __hip_bfloat16 P[4][16][76];

    const int bx   = blockIdx.x;
    const int h    = bx & 15;
    const int qb   = 31 - (bx >> 4);          // long-window blocks dispatched first
    const int i0   = qb * 64;
    const int hk   = h >> 1;
    const int tid  = threadIdx.x, wave = tid >> 6, lane = tid & 63;
    const int quad = lane >> 4, l15 = lane & 15;
    const int ib   = i0 + wave * 16;

    const __hip_bfloat16* Kh = Kn + hk * HDIM;              // row stride 1024
    const __hip_bfloat16* Vh = Vt + (size_t)(hk * HDIM) * 2048;

    // Q fragments (A-operand), fixed for the block
    bf16x8 qf[4];
    const __hip_bfloat16* qbase = Qn + (size_t)(ib + l15)*2048 + h*HDIM + quad*8;
#pragma unroll
    for (int kk = 0; kk < 4; ++kk) qf[kk] = *(const bf16x8*)(qbase + kk*32);

    f32x4 o[8] = {};
    float lrow[4] = {0.f, 0.f, 0.f, 0.f};

    int j_lo = i0 - WIN; if (j_lo < 0) j_lo = 0;
    const int jstart = j_lo & ~63;
    const int jend   = i0;                    // diagonal tile start

    // ---- cooperative staging of one (K,V) tile pair into buffer b ----
    auto stage = [&](int b, int j0) {
#pragma unroll
        for (int p = 0; p < 4; ++p) {         // K: 64 rows x 16 chunks of 16B
            int L = p*256 + tid;
            int r = L >> 4;
            int c = (L & 15) ^ (r & 15);      // XOR swizzle
            gld16((char*)&Ksm[b][0] + L*16, Kh + (size_t)(j0 + r)*1024 + c*8);
        }
#pragma unroll
        for (int p = 0; p < 4; ++p) {         // V: 128 d-rows x 8 chunks of 16B
            int L = p*256 + tid;
            int dv = L >> 3;
            int c = (L & 7) ^ (dv & 7);       // XOR swizzle
            gld16((char*)&Vsm[b][0] + L*16, Vh + (size_t)dv*2048 + j0 + c*8);
        }
    };

    stage(0, jstart);
    int cur = 0;
    for (int j0 = jstart; j0 <= jend; j0 += 64, cur ^= 1) {
        __syncthreads();                      // drains staging vmcnt + syncs buffers
        if (j0 + 64 <= jend) stage(cur ^ 1, j0 + 64);

        // ---- S = Q K^T (16 x 64 per wave), frags from swizzled LDS ----
        f32x4 sacc[4] = {};
#pragma unroll
        for (int nt = 0; nt < 4; ++nt) {
            const int r = nt*16 + l15;
#pragma unroll
            for (int kk = 0; kk < 4; ++kk) {
                const int cc = (kk*4 + quad) ^ l15;   // swizzled chunk
                bf16x8 kfr = *(const bf16x8*)(&Ksm[cur][0] + r*128 + cc*8);
                sacc[nt] = __builtin_amdgcn_mfma_f32_16x16x32_bf16(qf[kk], kfr, sacc[nt], 0, 0, 0);
            }
        }

        // ---- p = exp2(s), P write, per-lane row-sum ----
        const bool need_mask = (j0 + 63 > ib) || (j0 < ib + 15 - WIN);
        if (need_mask) {
#pragma unroll
            for (int nt = 0; nt < 4; ++nt) {
                int j = j0 + nt*16 + l15;
#pragma unroll
                for (int r = 0; r < 4; ++r) {
                    int i = ib + quad*4 + r;
                    bool valid = (j <= i) && (i - j <= WIN);
                    float p = valid ? __builtin_exp2f(sacc[nt][r]) : 0.f;
                    lrow[r] += p;
                    P[wave][quad*4 + r][nt*16 + l15] = __float2bfloat16(p);
                }
            }
        } else {
#pragma unroll
            for (int nt = 0; nt < 4; ++nt)
#pragma unroll
                for (int r = 0; r < 4; ++r) {
                    float p = __builtin_exp2f(sacc[nt][r]);
                    lrow[r] += p;
                    P[wave][quad*4 + r][nt*16 + l15] = __float2bfloat16(p);
                }
        }

        // ---- O += P V (P per-wave, lgkm-ordered; V frags from swizzled LDS) ----
#pragma unroll
        for (int ks = 0; ks < 2; ++ks) {
            bf16x8 pf = *(const bf16x8*)&P[wave][l15][ks*32 + quad*8];
#pragma unroll
            for (int dt = 0; dt < 8; ++dt) {
                const int dv = dt*16 + l15;
                const int cc = (ks*4 + quad) ^ (l15 & 7);
                bf16x8 vfr = *(const bf16x8*)(&Vsm[cur][0] + dv*64 + cc*8);
                o[dt] = __builtin_amdgcn_mfma_f32_16x16x32_bf16(pf, vfr, o[dt], 0, 0, 0);
            }
        }
    }

    // ---- epilogue: single cross-lane reduce of lrow, normalize, store ----
#pragma unroll
    for (int r = 0; r < 4; ++r) {
        lrow[r] += __shfl_xor(lrow[r], 1);
        lrow[r] += __shfl_xor(lrow[r], 2);
        lrow[r] += __shfl_xor(lrow[r], 4);
        lrow[r] += __shfl_xor(lrow[r], 8);
        float inv = 1.0f / lrow[r];
        int row = ib + quad*4 + r;
#pragma unroll
        for (int dt = 0; dt < 8; ++dt)
            O[(size_t)row*2048 + h*HDIM + dt*16 + l15] = __float2bfloat16(o[dt][r] * inv);
    }
}

// ---------------------------------------------------------------------------
extern "C" void kernel_launch(void* const* d_in, const int* in_sizes, int n_in,
                              void* d_out, int out_size, void* d_ws, size_t ws_size,
                              hipStream_t stream)
{
    (void)in_sizes; (void)n_in; (void)out_size; (void)ws_size;
    const float* hs   = (const float*)d_in[0];
    const float* cosb = (const float*)d_in[1];
    const float* sinb = (const float*)d_in[2];
    const float* Wq   = (const float*)d_in[3];
    const float* Wk   = (const float*)d_in[4];
    const float* Wv   = (const float*)d_in[5];
    const float* Wo   = (const float*)d_in[6];
    const float* qs   = (const float*)d_in[7];
    const float* ks   = (const float*)d_in[8];

    char* ws = (char*)d_ws;
    __hip_bfloat16* WqkvT = (__hip_bfloat16*)(ws);
    __hip_bfloat16* WoT   = (__hip_bfloat16*)(ws + (16u << 20));
    __hip_bfloat16* QKV   = (__hip_bfloat16*)(ws + (24u << 20));
    __hip_bfloat16* Qn    = (__hip_bfloat16*)(ws + (40u << 20));
    __hip_bfloat16* Kn    = (__hip_bfloat16*)(ws + (48u << 20));
    __hip_bfloat16* Vt    = (__hip_bfloat16*)(ws + (52u << 20));
    __hip_bfloat16* hsb   = (__hip_bfloat16*)(ws + (56u << 20)); // overlaid with AT
    __hip_bfloat16* AT    = (__hip_bfloat16*)(ws + (56u << 20)); // disjoint liveness

    trans_cvt_kernel<<<dim3(5120), dim3(256), 0, stream>>>(Wq, Wk, Wv, Wo, hs, WqkvT, WoT, hsb);
    gemm_bt_kernel<__hip_bfloat16><<<dim3(64, 16), dim3(256), 0, stream>>>(hsb, WqkvT, QKV, 2048, 4096, 2048);
    rms_vt_kernel<<<dim3(2560), dim3(256), 0, stream>>>(QKV, cosb, sinb, qs, ks, Qn, Kn, Vt);
    attn_kernel<<<dim3(512), dim3(256), 0, stream>>>(Qn, Kn, Vt, AT);
    gemm_bt_kernel<float><<<dim3(32, 16), dim3(256), 0, stream>>>(AT, WoT, (float*)d_out, 2048, 2048, 2048);
}

// Round 8
// 230.222 us; speedup vs baseline: 1.5905x; 1.0912x over previous
//
#include <hip/hip_runtime.h>
#include <hip/hip_bf16.h>
#include <cmath>

// I/O: all inputs float32 (per reference setup_inputs), output float32.
// Internal compute: bf16 MFMA with fp32 accumulation.
//
// Workspace layout (64 MB total):
//  [0,16M)   WqkvT  [4096][2048] bf16   (rows: 0-2047 WqT, 2048-3071 WkT, 3072-4095 WvT)
//  [16,24M)  WoT    [2048][2048] bf16
//  [24,40M)  QKVraw [2048][4096] bf16
//  [40,48M)  Qn     [2048][2048] bf16   (post rms+rope, pre-scaled by QK_SCALE*log2e)
//  [48,52M)  Kn     [2048][1024] bf16
//  [52,56M)  Vt     [1024][2048] bf16   ([hkv*128 d][s])
//  [56,64M)  hsb    [2048][2048] bf16   (live: kernels 1-2)   }  overlaid,
//  [56,64M)  AT     [2048][2048] bf16   (live: kernels 4-5)   }  disjoint liveness

typedef __bf16 bf16x8 __attribute__((ext_vector_type(8)));
typedef float  f32x4  __attribute__((ext_vector_type(4)));

#define S_LEN    2048
#define NH       16
#define NKV      8
#define HDIM     128
#define WIN      1024
// QK_SCALE * log2(e): scores computed directly in log2 domain -> exp2
#define QK_SCALE_L2E 0.12751744595f
#define RMS_EPS  1e-6f

__device__ __forceinline__ void gld16(void* lds, const void* g) {
    __builtin_amdgcn_global_load_lds(
        (const __attribute__((address_space(1))) unsigned int*)g,
        (__attribute__((address_space(3))) unsigned int*)lds, 16, 0, 0);
}

__device__ __forceinline__ unsigned short f2bu(float x) {
    __hip_bfloat16 h = __float2bfloat16(x);
    return *(unsigned short*)&h;
}

// ---------------------------------------------------------------------------
// Fused: weight transpose + f32->bf16 (blocks 0..3071)  AND
//        hidden_states f32->bf16 convert (blocks 3072..5119).
// ---------------------------------------------------------------------------
__global__ __launch_bounds__(256) void trans_cvt_kernel(
    const float* __restrict__ Wq, const float* __restrict__ Wk,
    const float* __restrict__ Wv, const float* __restrict__ Wo,
    const float* __restrict__ hs,
    __hip_bfloat16* __restrict__ WqkvT, __hip_bfloat16* __restrict__ WoT,
    __hip_bfloat16* __restrict__ hsb)
{
    __shared__ __attribute__((aligned(16))) unsigned short tile[64][72]; // 144B rows
    int id = blockIdx.x;
    if (id >= 3072) {   // ---- hidden_states convert: 8 elems/thread ----
        size_t i = ((size_t)(id - 3072) * 256 + threadIdx.x) * 8;
        float4 a = *(const float4*)(hs + i);
        float4 b = *(const float4*)(hs + i + 4);
        unsigned short u[8] = { f2bu(a.x), f2bu(a.y), f2bu(a.z), f2bu(a.w),
                                f2bu(b.x), f2bu(b.y), f2bu(b.z), f2bu(b.w) };
        *(uint4*)(hsb + i) = *(uint4*)u;
        return;
    }
    const float* src; __hip_bfloat16* dst; int N, kt, nt;
    if (id < 1024)      { src = Wq; dst = WqkvT;                          N = 2048; kt = id >> 5;          nt = id & 31; }
    else if (id < 1536) { src = Wk; dst = WqkvT + (size_t)2048*2048;      N = 1024; kt = (id-1024) >> 4;   nt = (id-1024) & 15; }
    else if (id < 2048) { src = Wv; dst = WqkvT + (size_t)3072*2048;      N = 1024; kt = (id-1536) >> 4;   nt = (id-1536) & 15; }
    else                { src = Wo; dst = WoT;                            N = 2048; kt = (id-2048) >> 5;   nt = (id-2048) & 31; }
    int k0 = kt * 64, n0 = nt * 64;
    int tid = threadIdx.x;
#pragma unroll
    for (int p = 0; p < 2; ++p) {
        int c = p*256 + tid; int r = c >> 3, cc = (c & 7) * 8;
        const float* s = src + (size_t)(k0 + r)*N + n0 + cc;
        float4 a = *(const float4*)s;
        float4 b = *(const float4*)(s + 4);
        unsigned short u[8] = { f2bu(a.x), f2bu(a.y), f2bu(a.z), f2bu(a.w),
                                f2bu(b.x), f2bu(b.y), f2bu(b.z), f2bu(b.w) };
        *(uint4*)&tile[r][cc] = *(uint4*)u;
    }
    __syncthreads();
#pragma unroll
    for (int p = 0; p < 2; ++p) {
        int c = p*256 + tid; int r2 = c >> 3, c2 = (c & 7) * 8;
        uint4 o;
        o.x = tile[c2+0][r2] | ((unsigned)tile[c2+1][r2] << 16);
        o.y = tile[c2+2][r2] | ((unsigned)tile[c2+3][r2] << 16);
        o.z = tile[c2+4][r2] | ((unsigned)tile[c2+5][r2] << 16);
        o.w = tile[c2+6][r2] | ((unsigned)tile[c2+7][r2] << 16);
        *(uint4*)(dst + (size_t)(n0 + r2)*2048 + k0 + c2) = o;
    }
}

// ---------------------------------------------------------------------------
// GEMM: C[M][N] = A[M][K] * BT[N][K]^T.
// Round-8: BM=128 x BN=128, BK=64, DOUBLE-BUFFERED LDS (64 KB), 4 waves
// (2x2, wave-tile 64x64 -> 0.5 ds_read_b128 per MFMA, the best ratio of
// this family).  Structure: sync; stage(next buf); compute(cur buf) —
// the staging issued after each barrier has the whole compute phase
// (~1200 cyc) to complete before the next barrier's vmcnt(0) drain, so
// the m97-style per-iteration drain stall is gone (same shape that fixed
// the attention kernel).  BK=64 also halves barrier count (32 iters).
// XOR swizzle: chunk c of row r at slot c^(r&7); fragment slot
// (ks*4+quad)^(l15&7) is lane-constant; 8 slots x 2 lanes = 2/bank = free.
// ---------------------------------------------------------------------------
template <typename OT>
__global__ __launch_bounds__(256, 2) void gemm_bt_kernel(
    const __hip_bfloat16* __restrict__ A, const __hip_bfloat16* __restrict__ BT,
    OT* __restrict__ C, int M, int N, int K)
{
    __shared__ __attribute__((aligned(16))) __hip_bfloat16 As[2][128*64];  // 2x16KB
    __shared__ __attribute__((aligned(16))) __hip_bfloat16 Bs[2][128*64];  // 2x16KB
    const int tid  = threadIdx.x;
    const int lane = tid & 63;
    const int wave = tid >> 6;
    const int quad = lane >> 4, l15 = lane & 15;
    const int m0 = blockIdx.y * 128, n0 = blockIdx.x * 128;
    const int wm = (wave >> 1) * 64, wn = (wave & 1) * 64;
    const int sw = l15 & 7;                     // row-parity xor term (lane-const)

    f32x4 acc[4][4] = {};

    // stage one BK=64 tile pair into buffer b (8 x gld16 per thread)
    auto stage = [&](int b, int k0) {
#pragma unroll
        for (int p = 0; p < 4; ++p) {           // A: 128 rows x 8 slots of 16B
            int L = p*256 + tid;
            int r = L >> 3, s = L & 7;
            int cs = s ^ (r & 7);
            gld16((char*)&As[b][0] + L*16, A + (size_t)(m0 + r)*K + k0 + cs*8);
        }
#pragma unroll
        for (int p = 0; p < 4; ++p) {           // B: 128 rows x 8 slots of 16B
            int L = p*256 + tid;
            int r = L >> 3, s = L & 7;
            int cs = s ^ (r & 7);
            gld16((char*)&Bs[b][0] + L*16, BT + (size_t)(n0 + r)*K + k0 + cs*8);
        }
    };

    const int NT = K >> 6;
    stage(0, 0);
    int cur = 0;
    for (int kt = 0; kt < NT; ++kt, cur ^= 1) {
        __syncthreads();                        // staging for cur done; waves synced
        if (kt + 1 < NT) stage(cur ^ 1, (kt + 1) << 6);
#pragma unroll
        for (int ks = 0; ks < 2; ++ks) {        // two 32-k steps within BK=64
            const int slot = ((ks*4 + quad) ^ sw) * 8;
            bf16x8 af[4], bfr[4];
#pragma unroll
            for (int t = 0; t < 4; ++t) {
                af[t]  = *(const bf16x8*)(&As[cur][0] + (wm + t*16 + l15)*64 + slot);
                bfr[t] = *(const bf16x8*)(&Bs[cur][0] + (wn + t*16 + l15)*64 + slot);
            }
#pragma unroll
            for (int mt = 0; mt < 4; ++mt)
#pragma unroll
                for (int nt = 0; nt < 4; ++nt)
                    acc[mt][nt] = __builtin_amdgcn_mfma_f32_16x16x32_bf16(af[mt], bfr[nt], acc[mt][nt], 0, 0, 0);
        }
    }
#pragma unroll
    for (int mt = 0; mt < 4; ++mt)
#pragma unroll
        for (int nt = 0; nt < 4; ++nt)
#pragma unroll
            for (int r = 0; r < 4; ++r) {
                int row = m0 + wm + mt*16 + quad*4 + r;
                int col = n0 + wn + nt*16 + l15;
                if constexpr (__is_same(OT, float))
                    C[(size_t)row*N + col] = acc[mt][nt][r];
                else
                    C[(size_t)row*N + col] = __float2bfloat16(acc[mt][nt][r]);
            }
}

// ---------------------------------------------------------------------------
// Fused: RMSNorm+RoPE on Q,K rows of QKVraw (blocks 0..2047, one s each)
//        AND V transpose QKVraw -> Vt (blocks 2048..2559, 64x64 tiles).
// Q output pre-scaled by QK_SCALE*log2(e) (attention uses exp2 directly).
// ---------------------------------------------------------------------------
__global__ __launch_bounds__(256) void rms_vt_kernel(
    const __hip_bfloat16* __restrict__ qkv,
    const float* __restrict__ cosb, const float* __restrict__ sinb,
    const float* __restrict__ qsc,  const float* __restrict__ ksc,
    __hip_bfloat16* __restrict__ Qn, __hip_bfloat16* __restrict__ Kn,
    __hip_bfloat16* __restrict__ Vt)
{
    __shared__ __attribute__((aligned(16))) unsigned short tile[64][72];
    int id = blockIdx.x;
    if (id >= 2048) {   // ---- V transpose tile ----
        int t  = id - 2048;                 // 512 tiles: 32 (s) x 16 (v)
        int s0 = (t & 31) * 64;
        int v0 = (t >> 5) * 64;
        int tid = threadIdx.x;
#pragma unroll
        for (int p = 0; p < 2; ++p) {
            int c = p*256 + tid; int r = c >> 3, cc = (c & 7) * 8;
            uint4 v = *(const uint4*)(qkv + (size_t)(s0 + r)*4096 + 3072 + v0 + cc);
            *(uint4*)&tile[r][cc] = v;
        }
        __syncthreads();
#pragma unroll
        for (int p = 0; p < 2; ++p) {
            int c = p*256 + tid; int r2 = c >> 3, c2 = (c & 7) * 8;
            uint4 o;
            o.x = tile[c2+0][r2] | ((unsigned)tile[c2+1][r2] << 16);
            o.y = tile[c2+2][r2] | ((unsigned)tile[c2+3][r2] << 16);
            o.z = tile[c2+4][r2] | ((unsigned)tile[c2+5][r2] << 16);
            o.w = tile[c2+6][r2] | ((unsigned)tile[c2+7][r2] << 16);
            *(uint4*)(Vt + (size_t)(v0 + r2)*2048 + s0 + c2) = o;
        }
        return;
    }
    // ---- RMSNorm + RoPE ----
    int s = id;
    int wave = threadIdx.x >> 6, lane = threadIdx.x & 63;
    float c1 = cosb[s*128 + lane];
    float c2 = cosb[s*128 + 64 + lane];
    float s1 = sinb[s*128 + lane];
    float s2 = sinb[s*128 + 64 + lane];
    for (int u = wave; u < 24; u += 4) {
        bool isq = (u < 16);
        int h = isq ? u : u - 16;
        const __hip_bfloat16* x = qkv + (size_t)s*4096 + (isq ? h*128 : 2048 + h*128);
        float x1 = (float)x[lane], x2 = (float)x[lane + 64];
        float ss = x1*x1 + x2*x2;
#pragma unroll
        for (int off = 32; off; off >>= 1) ss += __shfl_xor(ss, off);
        float r = rsqrtf(ss * (1.0f/128.0f) + RMS_EPS);
        if (isq) r *= QK_SCALE_L2E;        // fold attn scale + log2e into Q
        const float* sc = isq ? qsc : ksc;
        float y1 = x1 * r * sc[lane];
        float y2 = x2 * r * sc[lane + 64];
        float o1 = y1*c1 - y2*s1;   // d < 64:  x*c - x[d+64]*s
        float o2 = y2*c2 + y1*s2;   // d >= 64: x*c + x[d-64]*s
        __hip_bfloat16* dst = isq ? (Qn + (size_t)s*2048 + h*128)
                                  : (Kn + (size_t)s*1024 + h*128);
        dst[lane]      = __float2bfloat16(o1);
        dst[lane + 64] = __float2bfloat16(o2);
    }
}

// ---------------------------------------------------------------------------
// Flash attention, sliding-window causal — m97-style LDS staging.
//  * Block = 4 waves x 16 q-rows = 64 q-rows of one head; grid 512 (2 blk/CU).
//  * K/V tiles staged into double-buffered LDS via global_load_lds width=16.
//  * XOR-swizzled LDS layouts; one barrier per tile; next staging issued
//    right after it (double buffer overlaps full tile compute).
//  * No online max (scores bounded by RMS-norm); p=exp2(s), per-lane row
//    sums, single cross-lane reduce in epilogue.
// ---------------------------------------------------------------------------
__global__ __launch_bounds__(256, 2) void attn_kernel(
    const __hip_bfloat16* __restrict__ Qn,  // [S][2048], pre-scaled (log2 domain)
    const __hip_bfloat16* __restrict__ Kn,  // [S][1024]
    const __hip_bfloat16* __restrict__ Vt,  // [1024][S]
    __hip_bfloat16* __restrict__ O)         // [S][2048]
{
    __shared__ __attribute__((aligned(16))) __hip_bfloat16 Ksm[2][64*128];  // 2x16KB
    __shared__ __attribute__((aligned(16))) __hip_bfloat16 Vsm[2][128*64];  // 2x16KB
    __shared__ __attribute__((aligned(16))) __hip_bfloat16 P[4][16][76];

    const int bx   = blockIdx.x;
    const int h    = bx & 15;
    const int qb   = 31 - (bx >> 4);          // long-window blocks dispatched first
    const int i0   = qb * 64;
    const int hk   = h >> 1;
    const int tid  = threadIdx.x, wave = tid >> 6, lane = tid & 63;
    const int quad = lane >> 4, l15 = lane & 15;
    const int ib   = i0 + wave * 16;

    const __hip_bfloat16* Kh = Kn + hk * HDIM;              // row stride 1024
    const __hip_bfloat16* Vh = Vt + (size_t)(hk * HDIM) * 2048;

    // Q fragments (A-operand), fixed for the block
    bf16x8 qf[4];
    const __hip_bfloat16* qbase = Qn + (size_t)(ib + l15)*2048 + h*HDIM + quad*8;
#pragma unroll
    for (int kk = 0; kk < 4; ++kk) qf[kk] = *(const bf16x8*)(qbase + kk*32);

    f32x4 o[8] = {};
    float lrow[4] = {0.f, 0.f, 0.f, 0.f};

    int j_lo = i0 - WIN; if (j_lo < 0) j_lo = 0;
    const int jstart = j_lo & ~63;
    const int jend   = i0;                    // diagonal tile start

    // ---- cooperative staging of one (K,V) tile pair into buffer b ----
    auto stage = [&](int b, int j0) {
#pragma unroll
        for (int p = 0; p < 4; ++p) {         // K: 64 rows x 16 chunks of 16B
            int L = p*256 + tid;
            int r = L >> 4;
            int c = (L & 15) ^ (r & 15);      // XOR swizzle
            gld16((char*)&Ksm[b][0] + L*16, Kh + (size_t)(j0 + r)*1024 + c*8);
        }
#pragma unroll
        for (int p = 0; p < 4; ++p) {         // V: 128 d-rows x 8 chunks of 16B
            int L = p*256 + tid;
            int dv = L >> 3;
            int c = (L & 7) ^ (dv & 7);       // XOR swizzle
            gld16((char*)&Vsm[b][0] + L*16, Vh + (size_t)dv*2048 + j0 + c*8);
        }
    };

    stage(0, jstart);
    int cur = 0;
    for (int j0 = jstart; j0 <= jend; j0 += 64, cur ^= 1) {
        __syncthreads();                      // drains staging vmcnt + syncs buffers
        if (j0 + 64 <= jend) stage(cur ^ 1, j0 + 64);

        // ---- S = Q K^T (16 x 64 per wave), frags from swizzled LDS ----
        f32x4 sacc[4] = {};
#pragma unroll
        for (int nt = 0; nt < 4; ++nt) {
            const int r = nt*16 + l15;
#pragma unroll
            for (int kk = 0; kk < 4; ++kk) {
                const int cc = (kk*4 + quad) ^ l15;   // swizzled chunk
                bf16x8 kfr = *(const bf16x8*)(&Ksm[cur][0] + r*128 + cc*8);
                sacc[nt] = __builtin_amdgcn_mfma_f32_16x16x32_bf16(qf[kk], kfr, sacc[nt], 0, 0, 0);
            }
        }

        // ---- p = exp2(s), P write, per-lane row-sum ----
        const bool need_mask = (j0 + 63 > ib) || (j0 < ib + 15 - WIN);
        if (need_mask) {
#pragma unroll
            for (int nt = 0; nt < 4; ++nt) {
                int j = j0 + nt*16 + l15;
#pragma unroll
                for (int r = 0; r < 4; ++r) {
                    int i = ib + quad*4 + r;
                    bool valid = (j <= i) && (i - j <= WIN);
                    float p = valid ? __builtin_exp2f(sacc[nt][r]) : 0.f;
                    lrow[r] += p;
                    P[wave][quad*4 + r][nt*16 + l15] = __float2bfloat16(p);
                }
            }
        } else {
#pragma unroll
            for (int nt = 0; nt < 4; ++nt)
#pragma unroll
                for (int r = 0; r < 4; ++r) {
                    float p = __builtin_exp2f(sacc[nt][r]);
                    lrow[r] += p;
                    P[wave][quad*4 + r][nt*16 + l15] = __float2bfloat16(p);
                }
        }

        // ---- O += P V (P per-wave, lgkm-ordered; V frags from swizzled LDS) ----
#pragma unroll
        for (int ks = 0; ks < 2; ++ks) {
            bf16x8 pf = *(const bf16x8*)&P[wave][l15][ks*32 + quad*8];
#pragma unroll
            for (int dt = 0; dt < 8; ++dt) {
                const int dv = dt*16 + l15;
                const int cc = (ks*4 + quad) ^ (l15 & 7);
                bf16x8 vfr = *(const bf16x8*)(&Vsm[cur][0] + dv*64 + cc*8);
                o[dt] = __builtin_amdgcn_mfma_f32_16x16x32_bf16(pf, vfr, o[dt], 0, 0, 0);
            }
        }
    }

    // ---- epilogue: single cross-lane reduce of lrow, normalize, store ----
#pragma unroll
    for (int r = 0; r < 4; ++r) {
        lrow[r] += __shfl_xor(lrow[r], 1);
        lrow[r] += __shfl_xor(lrow[r], 2);
        lrow[r] += __shfl_xor(lrow[r], 4);
        lrow[r] += __shfl_xor(lrow[r], 8);
        float inv = 1.0f / lrow[r];
        int row = ib + quad*4 + r;
#pragma unroll
        for (int dt = 0; dt < 8; ++dt)
            O[(size_t)row*2048 + h*HDIM + dt*16 + l15] = __float2bfloat16(o[dt][r] * inv);
    }
}

// ---------------------------------------------------------------------------
extern "C" void kernel_launch(void* const* d_in, const int* in_sizes, int n_in,
                              void* d_out, int out_size, void* d_ws, size_t ws_size,
                              hipStream_t stream)
{
    (void)in_sizes; (void)n_in; (void)out_size; (void)ws_size;
    const float* hs   = (const float*)d_in[0];
    const float* cosb = (const float*)d_in[1];
    const float* sinb = (const float*)d_in[2];
    const float* Wq   = (const float*)d_in[3];
    const float* Wk   = (const float*)d_in[4];
    const float* Wv   = (const float*)d_in[5];
    const float* Wo   = (const float*)d_in[6];
    const float* qs   = (const float*)d_in[7];
    const float* ks   = (const float*)d_in[8];

    char* ws = (char*)d_ws;
    __hip_bfloat16* WqkvT = (__hip_bfloat16*)(ws);
    __hip_bfloat16* WoT   = (__hip_bfloat16*)(ws + (16u << 20));
    __hip_bfloat16* QKV   = (__hip_bfloat16*)(ws + (24u << 20));
    __hip_bfloat16* Qn    = (__hip_bfloat16*)(ws + (40u << 20));
    __hip_bfloat16* Kn    = (__hip_bfloat16*)(ws + (48u << 20));
    __hip_bfloat16* Vt    = (__hip_bfloat16*)(ws + (52u << 20));
    __hip_bfloat16* hsb   = (__hip_bfloat16*)(ws + (56u << 20)); // overlaid with AT
    __hip_bfloat16* AT    = (__hip_bfloat16*)(ws + (56u << 20)); // disjoint liveness

    trans_cvt_kernel<<<dim3(5120), dim3(256), 0, stream>>>(Wq, Wk, Wv, Wo, hs, WqkvT, WoT, hsb);
    gemm_bt_kernel<__hip_bfloat16><<<dim3(32, 16), dim3(256), 0, stream>>>(hsb, WqkvT, QKV, 2048, 4096, 2048);
    rms_vt_kernel<<<dim3(2560), dim3(256), 0, stream>>>(QKV, cosb, sinb, qs, ks, Qn, Kn, Vt);
    attn_kernel<<<dim3(512), dim3(256), 0, stream>>>(Qn, Kn, Vt, AT);
    gemm_bt_kernel<float><<<dim3(16, 16), dim3(256), 0, stream>>>(AT, WoT, (float*)d_out, 2048, 2048, 2048);
}